// Round 4
// baseline (1601.470 us; speedup 1.0000x reference)
//
#include <hip/hip_runtime.h>
#include <cstdint>
#include <cstddef>

typedef unsigned short u16;
typedef short bf16x8 __attribute__((ext_vector_type(8)));
typedef float f32x4 __attribute__((ext_vector_type(4)));

#define LN_EPS 1e-6f

// async global->LDS, 16B per lane; LDS dest is wave-uniform base + lane*16
#define GLD16(gsrc, ldst) \
    __builtin_amdgcn_global_load_lds( \
        (const __attribute__((address_space(1))) void*)(gsrc), \
        (__attribute__((address_space(3))) void*)(ldst), 16, 0, 0)

__device__ inline u16 f2bf(float f) {
    uint32_t x = __float_as_uint(f);
    uint32_t r = (x + 0x7fffu + ((x >> 16) & 1u)) >> 16;   // RNE
    return (u16)r;
}
__device__ inline float bf2f(u16 u) { return __uint_as_float(((uint32_t)u) << 16); }

// ---------------- block reductions (256 threads = 4 waves) ----------------
__device__ inline float blk_sum(float v, float* s) {
    #pragma unroll
    for (int o = 32; o > 0; o >>= 1) v += __shfl_xor(v, o);
    __syncthreads();
    if ((threadIdx.x & 63) == 0) s[threadIdx.x >> 6] = v;
    __syncthreads();
    return s[0] + s[1] + s[2] + s[3];
}
__device__ inline float blk_max(float v, float* s) {
    #pragma unroll
    for (int o = 32; o > 0; o >>= 1) v = fmaxf(v, __shfl_xor(v, o));
    __syncthreads();
    if ((threadIdx.x & 63) == 0) s[threadIdx.x >> 6] = v;
    __syncthreads();
    return fmaxf(fmaxf(s[0], s[1]), fmaxf(s[2], s[3]));
}

// =====================================================================
// 8-phase 256xBN GEMM (m201-template port, validated in R3).
// C[m][n] = sum_k A[m][k]*B[n][k], row-major k-contiguous.
// BN in {256,128}: 8 waves as 2(M)x4(N), per-wave 128 x BN/4.
// BK=64 staged as 2 k-halves (256x32 A, BNx32 B); double-buffered.
// Counted vmcnt ckpts (4 for BN=256, 3 for BN=128) at phases 2/4.
// LDS 16B-slot swizzle: slot ^= (row>>1)&3, applied on global SOURCE col
// (linear global_load_lds dest) and on the ds_read addr (rule #21).
// SEG: A/B base pointer selected per 1024-col K-segment (kt>>4), local
// k within segment — lets callers feed concat operands with no copy.
// Grid (N/BN, M/256, Z); Z split-K: A,B advance z*K elems (non-SEG only),
// C advances z*zCstride. Requires gridDim.x*gridDim.y % 8 == 0.
// MODE: 0 f32*scale | 1 f32 relu(acc+bias) | 2 f32 += relu(acc+bias)
//       | 4 bf16 hi/lo split store, scale applied iff col < scaleCols
// =====================================================================
#define CKPT_MID() do { if constexpr (BN == 256) asm volatile("s_waitcnt vmcnt(4)" ::: "memory"); \
                        else                     asm volatile("s_waitcnt vmcnt(3)" ::: "memory"); } while (0)

template<int BN, int MODE, bool SEG>
__global__ __launch_bounds__(512, 2) void gemm8_k(
    const u16* __restrict__ A0, const u16* __restrict__ A1, const u16* __restrict__ A2, int lda,
    const u16* __restrict__ B0, const u16* __restrict__ B1, const u16* __restrict__ B2, int ldb,
    float* __restrict__ Cf, u16* __restrict__ Cb, u16* __restrict__ Cb2,
    const float* __restrict__ bias, int ldc, int K, size_t zCstride,
    float scale, int scaleCols)
{
    constexpr int NFRAG = BN / 64;          // n-fragments per wave
    constexpr int BKH   = BN * 32;          // B per-kh elems
    constexpr int BUFE  = 16384 + BN * 64;  // elems per buffer (A 2kh + B 2kh)
    __shared__ u16 lds[2 * BUFE];

    const int tid  = threadIdx.x;
    const int lane = tid & 63, wid = tid >> 6;
    const int wr = wid >> 2, wc = wid & 3;
    const int fr = lane & 15, fg = lane >> 4;

    const int gx  = gridDim.x, nwg = gx * gridDim.y;
    const int bid = blockIdx.y * gx + blockIdx.x;
    const int wg  = (bid & 7) * (nwg >> 3) + (bid >> 3);   // XCD-contiguous
    const int n0  = (wg % gx) * BN, m0 = (wg / gx) * 256;

    const u16* Az = A0 + (size_t)blockIdx.z * K;
    const u16* Bz = B0 + (size_t)blockIdx.z * K;
    float* Cfz = Cf ? Cf + (size_t)blockIdx.z * zCstride : nullptr;

    // staging geometry: thread covers row sr (and sr+128 for 256-row tiles)
    const int sr = tid >> 2;
    const int kb = ((tid & 3) ^ ((sr >> 1) & 3)) * 8;   // pre-swizzled col

    f32x4 acc[8][NFRAG];
    {
        f32x4 z = {0.f, 0.f, 0.f, 0.f};
        #pragma unroll
        for (int m = 0; m < 8; m++)
            #pragma unroll
            for (int n = 0; n < NFRAG; n++) acc[m][n] = z;
    }

    const int NT = K >> 6;

    auto STAGE = [&](int buf, int isB, int kh, int kt) {
        const u16* s0;
        const int ld = isB ? ldb : lda;
        const int rb = isB ? n0 : m0;
        int k0;
        if constexpr (SEG) {
            const int sg = kt >> 4;                   // 1024-col segments
            if (isB) s0 = (sg == 0) ? B0 : ((sg == 1) ? B1 : B2);
            else     s0 = (sg == 0) ? A0 : ((sg == 1) ? A1 : A2);
            k0 = ((kt & 15) * 64) + kh * 32 + kb;
        } else {
            s0 = isB ? Bz : Az;
            k0 = kt * 64 + kh * 32 + kb;
        }
        u16* dst = &lds[buf * BUFE + (isB ? 16384 : 0) + kh * (isB ? BKH : 8192) + tid * 8];
        GLD16(s0 + (size_t)(rb + sr) * ld + k0, dst);
        if (!isB || BN == 256)
            GLD16(s0 + (size_t)(rb + 128 + sr) * ld + k0, dst + 4096);
    };

    // per-lane read bases (u16 units)
    const int swz   = (fg ^ ((fr >> 1) & 3)) * 8;
    const int baseA = (wr * 128 + fr) * 32 + swz;
    const int baseB = 16384 + (wc * (BN / 4) + fr) * 32 + swz;

    // prologue: A-kh0, B-kh0, A-kh1, B-kh1 of tile 0
    STAGE(0, 0, 0, 0); STAGE(0, 1, 0, 0); STAGE(0, 0, 1, 0); STAGE(0, 1, 1, 0);
    CKPT_MID();                                            // kh0 group landed
    __builtin_amdgcn_s_barrier();

    bf16x8 af[4], bv[NFRAG];

    for (int t = 0; t < NT; ++t) {
        const int  aO  = (t & 1) * BUFE;
        const int  nxt = (t & 1) ^ 1;
        const bool pre = (t + 1 < NT);

        // ---- phase 1: (ms=0, ks=0)
        #pragma unroll
        for (int m = 0; m < 4; m++) af[m] = *(const bf16x8*)&lds[baseA + aO + m * 512];
        #pragma unroll
        for (int n = 0; n < NFRAG; n++) bv[n] = *(const bf16x8*)&lds[baseB + aO + n * 512];
        if (pre) STAGE(nxt, 0, 0, t + 1);
        __builtin_amdgcn_s_barrier();
        asm volatile("s_waitcnt lgkmcnt(0)" ::: "memory");
        __builtin_amdgcn_sched_barrier(0);
        __builtin_amdgcn_s_setprio(1);
        #pragma unroll
        for (int m = 0; m < 4; m++)
            #pragma unroll
            for (int n = 0; n < NFRAG; n++)
                acc[m][n] = __builtin_amdgcn_mfma_f32_16x16x32_bf16(af[m], bv[n], acc[m][n], 0, 0, 0);
        __builtin_amdgcn_s_setprio(0);
        __builtin_amdgcn_s_barrier();

        // ---- phase 2: (ms=1, ks=0); ckpt kh1(t)
        #pragma unroll
        for (int m = 0; m < 4; m++) af[m] = *(const bf16x8*)&lds[baseA + aO + (4 + m) * 512];
        if (pre) STAGE(nxt, 1, 0, t + 1);
        __builtin_amdgcn_s_barrier();
        asm volatile("s_waitcnt lgkmcnt(0)" ::: "memory");
        __builtin_amdgcn_sched_barrier(0);
        __builtin_amdgcn_s_setprio(1);
        #pragma unroll
        for (int m = 0; m < 4; m++)
            #pragma unroll
            for (int n = 0; n < NFRAG; n++)
                acc[4 + m][n] = __builtin_amdgcn_mfma_f32_16x16x32_bf16(af[m], bv[n], acc[4 + m][n], 0, 0, 0);
        __builtin_amdgcn_s_setprio(0);
        if (pre) { CKPT_MID(); }
        else     { asm volatile("s_waitcnt vmcnt(0)" ::: "memory"); }
        __builtin_amdgcn_sched_barrier(0);
        __builtin_amdgcn_s_barrier();

        // ---- phase 3: (ms=0, ks=1)
        #pragma unroll
        for (int m = 0; m < 4; m++) af[m] = *(const bf16x8*)&lds[baseA + aO + 8192 + m * 512];
        #pragma unroll
        for (int n = 0; n < NFRAG; n++) bv[n] = *(const bf16x8*)&lds[baseB + aO + BKH + n * 512];
        if (pre) STAGE(nxt, 0, 1, t + 1);
        __builtin_amdgcn_s_barrier();
        asm volatile("s_waitcnt lgkmcnt(0)" ::: "memory");
        __builtin_amdgcn_sched_barrier(0);
        __builtin_amdgcn_s_setprio(1);
        #pragma unroll
        for (int m = 0; m < 4; m++)
            #pragma unroll
            for (int n = 0; n < NFRAG; n++)
                acc[m][n] = __builtin_amdgcn_mfma_f32_16x16x32_bf16(af[m], bv[n], acc[m][n], 0, 0, 0);
        __builtin_amdgcn_s_setprio(0);
        __builtin_amdgcn_s_barrier();

        // ---- phase 4: (ms=1, ks=1); ckpt kh0(t+1)
        #pragma unroll
        for (int m = 0; m < 4; m++) af[m] = *(const bf16x8*)&lds[baseA + aO + 8192 + (4 + m) * 512];
        if (pre) STAGE(nxt, 1, 1, t + 1);
        __builtin_amdgcn_s_barrier();
        asm volatile("s_waitcnt lgkmcnt(0)" ::: "memory");
        __builtin_amdgcn_sched_barrier(0);
        __builtin_amdgcn_s_setprio(1);
        #pragma unroll
        for (int m = 0; m < 4; m++)
            #pragma unroll
            for (int n = 0; n < NFRAG; n++)
                acc[4 + m][n] = __builtin_amdgcn_mfma_f32_16x16x32_bf16(af[m], bv[n], acc[4 + m][n], 0, 0, 0);
        __builtin_amdgcn_s_setprio(0);
        if (pre) { CKPT_MID(); }
        __builtin_amdgcn_sched_barrier(0);
        __builtin_amdgcn_s_barrier();
    }

    // epilogue: D layout col = lane&15, row = (lane>>4)*4 + reg [HW-verified]
    #pragma unroll
    for (int m = 0; m < 8; m++)
        #pragma unroll
        for (int n = 0; n < NFRAG; n++)
            #pragma unroll
            for (int r = 0; r < 4; r++) {
                int row = m0 + wr * 128 + m * 16 + fg * 4 + r;
                int col = n0 + wc * (BN / 4) + n * 16 + fr;
                size_t idx = (size_t)row * ldc + col;
                float v = acc[m][n][r];
                if (MODE == 4) v *= (col < scaleCols) ? scale : 1.0f;
                else           v *= scale;
                if (MODE == 0) {
                    Cfz[idx] = v;
                } else if (MODE == 1) {
                    Cfz[idx] = fmaxf(v + bias[col], 0.f);
                } else if (MODE == 2) {
                    Cfz[idx] += fmaxf(v + bias[col], 0.f);
                } else {
                    u16 h = f2bf(v);
                    Cb[idx]  = h;
                    Cb2[idx] = f2bf(v - bf2f(h));
                }
            }
}

// ---------------- elementwise / converts ----------------
__global__ __launch_bounds__(256) void split_k(const float* __restrict__ s,
                                               u16* __restrict__ hi, u16* __restrict__ lo) {
    int i = blockIdx.x * 256 + threadIdx.x;
    const float4* sf = reinterpret_cast<const float4*>(s);
    float4 a = sf[2 * i], b = sf[2 * i + 1];
    float vals[8] = {a.x, a.y, a.z, a.w, b.x, b.y, b.z, b.w};
    union { u16 u[8]; int4 v; } th, tl;
    #pragma unroll
    for (int k = 0; k < 8; k++) {
        u16 h = f2bf(vals[k]);
        th.u[k] = h;
        tl.u[k] = f2bf(vals[k] - bf2f(h));
    }
    reinterpret_cast<int4*>(hi)[i] = th.v;
    reinterpret_cast<int4*>(lo)[i] = tl.v;
}

// Wcat row layout: rows 0-1023 Wq, 1024-2047 Wk, 2048-3071 Wv; cols [h|h|l]
__global__ __launch_bounds__(256) void wcat_k(const float* __restrict__ Wq, const float* __restrict__ Wk,
                                              const float* __restrict__ Wv, u16* __restrict__ Wcat) {
    int i = blockIdx.x * 256 + threadIdx.x;    // 0..393215
    int s = i >> 17;
    int rc = i & 131071;
    int r = rc >> 7, c8 = rc & 127;
    const float* src = (s == 0 ? Wq : (s == 1 ? Wk : Wv)) + (size_t)r * 1024 + c8 * 8;
    float4 a = *reinterpret_cast<const float4*>(src);
    float4 b = *reinterpret_cast<const float4*>(src + 4);
    float vals[8] = {a.x, a.y, a.z, a.w, b.x, b.y, b.z, b.w};
    union { u16 u[8]; int4 v; } th, tl;
    #pragma unroll
    for (int k = 0; k < 8; k++) {
        u16 h = f2bf(vals[k]);
        th.u[k] = h;
        tl.u[k] = f2bf(vals[k] - bf2f(h));
    }
    u16* drow = Wcat + (size_t)(s * 1024 + r) * 3072 + c8 * 8;
    *reinterpret_cast<int4*>(drow)        = th.v;
    *reinterpret_cast<int4*>(drow + 1024) = th.v;
    *reinterpret_cast<int4*>(drow + 2048) = tl.v;
}

__global__ __launch_bounds__(256) void cvt_k(const float* __restrict__ s, u16* __restrict__ d) {
    int i = blockIdx.x * 256 + threadIdx.x;
    const float4* sf = reinterpret_cast<const float4*>(s);
    float4 a = sf[2 * i], b = sf[2 * i + 1];
    union { u16 u[8]; int4 v; } t;
    t.u[0] = f2bf(a.x); t.u[1] = f2bf(a.y); t.u[2] = f2bf(a.z); t.u[3] = f2bf(a.w);
    t.u[4] = f2bf(b.x); t.u[5] = f2bf(b.y); t.u[6] = f2bf(b.z); t.u[7] = f2bf(b.w);
    reinterpret_cast<int4*>(d)[i] = t.v;
}

// yb = bf16(y + y2)  (split-K PV reduction fused into the convert)
__global__ __launch_bounds__(256) void cvt2_k(const float* __restrict__ s0, const float* __restrict__ s1,
                                              u16* __restrict__ d) {
    int i = blockIdx.x * 256 + threadIdx.x;
    const float4* f0 = reinterpret_cast<const float4*>(s0);
    const float4* f1 = reinterpret_cast<const float4*>(s1);
    float4 a = f0[2 * i], b = f0[2 * i + 1];
    float4 c = f1[2 * i], e = f1[2 * i + 1];
    union { u16 u[8]; int4 v; } t;
    t.u[0] = f2bf(a.x + c.x); t.u[1] = f2bf(a.y + c.y);
    t.u[2] = f2bf(a.z + c.z); t.u[3] = f2bf(a.w + c.w);
    t.u[4] = f2bf(b.x + e.x); t.u[5] = f2bf(b.y + e.y);
    t.u[6] = f2bf(b.z + e.z); t.u[7] = f2bf(b.w + e.w);
    reinterpret_cast<int4*>(d)[i] = t.v;
}

// dbuf[i][:] = bf16(|x[i+shift][:] - x[i][:]|) for i<8188, else 0
__global__ __launch_bounds__(256) void diff_k(const float* __restrict__ x, u16* __restrict__ d, int shift) {
    int i4 = blockIdx.x * 256 + threadIdx.x;
    int row = i4 >> 8;
    const float4* xf = reinterpret_cast<const float4*>(x);
    ushort4 o;
    if (row < 8188) {
        float4 a = xf[i4 + (shift << 8)];
        float4 b = xf[i4];
        o.x = f2bf(fabsf(a.x - b.x));
        o.y = f2bf(fabsf(a.y - b.y));
        o.z = f2bf(fabsf(a.z - b.z));
        o.w = f2bf(fabsf(a.w - b.w));
    } else {
        o.x = o.y = o.z = o.w = 0;
    }
    reinterpret_cast<ushort4*>(d)[i4] = o;
}

__global__ __launch_bounds__(256) void tail_k(const float* __restrict__ x, float* __restrict__ mn) {
    int i = blockIdx.x * 256 + threadIdx.x;
    mn[8188 * 1024 + i] = x[8188 * 1024 + i];
}

// ---------------- softmax over a row of 8192 fp32 ----------------
__global__ __launch_bounds__(256) void softmax_k(const float* __restrict__ S,
                                                 float* __restrict__ aw, int row0) {
    __shared__ float red[4];
    int r = blockIdx.x, tid = threadIdx.x;
    const float4* src = reinterpret_cast<const float4*>(S + (size_t)r * 8192);
    float4 xv[8];
    float mx = -1e30f;
    #pragma unroll
    for (int j = 0; j < 8; j++) {
        xv[j] = src[tid + 256 * j];
        mx = fmaxf(mx, fmaxf(fmaxf(xv[j].x, xv[j].y), fmaxf(xv[j].z, xv[j].w)));
    }
    mx = blk_max(mx, red);
    float sum = 0.f;
    #pragma unroll
    for (int j = 0; j < 8; j++) {
        xv[j].x = __expf(xv[j].x - mx); sum += xv[j].x;
        xv[j].y = __expf(xv[j].y - mx); sum += xv[j].y;
        xv[j].z = __expf(xv[j].z - mx); sum += xv[j].z;
        xv[j].w = __expf(xv[j].w - mx); sum += xv[j].w;
    }
    sum = blk_sum(sum, red);
    float inv = 1.0f / sum;
    float4* dst = reinterpret_cast<float4*>(aw + (size_t)(row0 + r) * 8192);
    #pragma unroll
    for (int j = 0; j < 8; j++) {
        float4 o;
        o.x = xv[j].x * inv; o.y = xv[j].y * inv; o.z = xv[j].z * inv; o.w = xv[j].w * inv;
        dst[tid + 256 * j] = o;
    }
}

// ---------------- transposes (64x64 tiles) ----------------
__global__ __launch_bounds__(256) void transpose_f32_bf16(const float* __restrict__ src,
                                                          u16* __restrict__ dst) {
    __shared__ u16 t[64][72];
    int r0 = blockIdx.y * 64, c0 = blockIdx.x * 64;
    int tid = threadIdx.x;
    #pragma unroll
    for (int p = 0; p < 4; p++) {
        int q = p * 256 + tid;
        int r = q >> 4, c4 = q & 15;
        float4 v = *(reinterpret_cast<const float4*>(src + (size_t)(r0 + r) * 8192 + c0) + c4);
        t[c4 * 4 + 0][r] = f2bf(v.x);
        t[c4 * 4 + 1][r] = f2bf(v.y);
        t[c4 * 4 + 2][r] = f2bf(v.z);
        t[c4 * 4 + 3][r] = f2bf(v.w);
    }
    __syncthreads();
    #pragma unroll
    for (int p = 0; p < 2; p++) {
        int q = p * 256 + tid;
        int rr = q >> 3, cc = q & 7;
        *reinterpret_cast<int4*>(dst + (size_t)(c0 + rr) * 8192 + r0 + cc * 8) =
            *reinterpret_cast<const int4*>(&t[rr][cc * 8]);
    }
}

// bf16 transpose with leading dims; grid (cols/64, rows/64)
__global__ __launch_bounds__(256) void transpose_bf16(const u16* __restrict__ src,
                                                      u16* __restrict__ dst,
                                                      int srcld, int dstld) {
    __shared__ u16 t[64][72];
    int r0 = blockIdx.y * 64, c0 = blockIdx.x * 64;
    int tid = threadIdx.x;
    #pragma unroll
    for (int p = 0; p < 2; p++) {
        int q = p * 256 + tid;
        int r = q >> 3, c8 = q & 7;
        int4 v = *(reinterpret_cast<const int4*>(src + (size_t)(r0 + r) * srcld + c0) + c8);
        const u16* u = reinterpret_cast<const u16*>(&v);
        #pragma unroll
        for (int k = 0; k < 8; k++) t[c8 * 8 + k][r] = u[k];
    }
    __syncthreads();
    #pragma unroll
    for (int p = 0; p < 2; p++) {
        int q = p * 256 + tid;
        int rr = q >> 3, cc = q & 7;
        *reinterpret_cast<int4*>(dst + (size_t)(c0 + rr) * dstld + r0 + cc * 8) =
            *reinterpret_cast<const int4*>(&t[rr][cc * 8]);
    }
}

// ---------------- LN kernels ----------------
__global__ __launch_bounds__(256) void ln_y_k(const float* __restrict__ y2, const float* __restrict__ mn,
                                              const float* __restrict__ g, const float* __restrict__ b,
                                              u16* __restrict__ zb) {
    __shared__ float red[4];
    int r = blockIdx.x, tid = threadIdx.x;
    float4 a = reinterpret_cast<const float4*>(y2 + (size_t)r * 1024)[tid];
    float4 c = reinterpret_cast<const float4*>(mn + (size_t)r * 1024)[tid];
    float4 v; v.x = a.x + c.x; v.y = a.y + c.y; v.z = a.z + c.z; v.w = a.w + c.w;
    float s  = v.x + v.y + v.z + v.w;
    float sq = v.x * v.x + v.y * v.y + v.z * v.z + v.w * v.w;
    s  = blk_sum(s, red);
    sq = blk_sum(sq, red);
    float mu = s * (1.0f / 1024.0f);
    float rs = rsqrtf(sq * (1.0f / 1024.0f) - mu * mu + LN_EPS);
    float4 gg = reinterpret_cast<const float4*>(g)[tid];
    float4 bb = reinterpret_cast<const float4*>(b)[tid];
    ushort4 o;
    o.x = f2bf((v.x - mu) * rs * gg.x + bb.x);
    o.y = f2bf((v.y - mu) * rs * gg.y + bb.y);
    o.z = f2bf((v.z - mu) * rs * gg.z + bb.z);
    o.w = f2bf((v.w - mu) * rs * gg.w + bb.w);
    reinterpret_cast<ushort4*>(zb + (size_t)r * 1024)[tid] = o;
}

__global__ __launch_bounds__(256) void ln_dot_k(const float* __restrict__ h, const float* __restrict__ g,
                                                const float* __restrict__ b, const float* __restrict__ kd,
                                                const float* __restrict__ kdb, float* __restrict__ out) {
    __shared__ float red[4];
    int r = blockIdx.x, tid = threadIdx.x;
    float4 v = reinterpret_cast<const float4*>(h + (size_t)r * 1024)[tid];
    float s  = v.x + v.y + v.z + v.w;
    float sq = v.x * v.x + v.y * v.y + v.z * v.z + v.w * v.w;
    s  = blk_sum(s, red);
    sq = blk_sum(sq, red);
    float mu = s * (1.0f / 1024.0f);
    float rs = rsqrtf(sq * (1.0f / 1024.0f) - mu * mu + LN_EPS);
    float4 gg = reinterpret_cast<const float4*>(g)[tid];
    float4 bb = reinterpret_cast<const float4*>(b)[tid];
    float4 kk = reinterpret_cast<const float4*>(kd)[tid];
    float part = ((v.x - mu) * rs * gg.x + bb.x) * kk.x
               + ((v.y - mu) * rs * gg.y + bb.y) * kk.y
               + ((v.z - mu) * rs * gg.z + bb.z) * kk.z
               + ((v.w - mu) * rs * gg.w + bb.w) * kk.w;
    part = blk_sum(part, red);
    if (tid == 0) out[r] = 1.0f / (1.0f + __expf(-(part + kdb[0])));
}

// ---------------- launch ----------------
extern "C" void kernel_launch(void* const* d_in, const int* in_sizes, int n_in,
                              void* d_out, int out_size, void* d_ws, size_t ws_size,
                              hipStream_t stream) {
    (void)in_sizes; (void)n_in; (void)out_size; (void)ws_size;
    const float* x    = (const float*)d_in[0];
    const float* Wq   = (const float*)d_in[2];
    const float* Wk   = (const float*)d_in[3];
    const float* Wv   = (const float*)d_in[4];
    const float* Wo   = (const float*)d_in[5];
    const float* fc1w = (const float*)d_in[6];
    const float* fc1b = (const float*)d_in[7];
    const float* kaw  = (const float*)d_in[8];
    const float* kab  = (const float*)d_in[9];
    const float* kdw  = (const float*)d_in[10];
    const float* kdb  = (const float*)d_in[11];
    const float* lyg  = (const float*)d_in[12];
    const float* lyb  = (const float*)d_in[13];
    const float* lkg  = (const float*)d_in[14];
    const float* lkb  = (const float*)d_in[15];

    float* out0 = (float*)d_out;
    float* aw   = out0 + 8192;

    char* base = (char*)d_ws;
    size_t off = 0;
    auto alloc = [&](size_t bytes) -> char* {
        char* p = base + off;
        off += (bytes + 255) & ~(size_t)255;
        return p;
    };
    const size_t NM = 8192ULL * 1024ULL;
    u16*   ST   = (u16*)alloc(8192ULL * 8192ULL * 2);   // 128MB; first 64MB doubles as Sf
    float* Sf   = (float*)ST;
    u16*   xh   = (u16*)alloc(NM * 2);
    u16*   xl   = (u16*)alloc(NM * 2);
    u16*   QKVh = (u16*)alloc(8192ULL * 3072ULL * 2);   // 50MB: cols [Q|K|V] hi
    u16*   QKVl = (u16*)alloc(8192ULL * 3072ULL * 2);   // 50MB: lo
    u16*   Vt   = (u16*)alloc(NM * 2);
    u16*   dbuf = (u16*)alloc(NM * 2);                  // later reused as zb
    u16*   yb   = (u16*)alloc(NM * 2);
    float* mn   = (float*)alloc(NM * 4);
    float* y    = (float*)alloc(NM * 4);                // later reused as h
    float* y2   = (float*)alloc(NM * 4);
    u16*   Wcat = (u16*)alloc(3072ULL * 3072ULL * 2);   // 18MB
    u16*   fwb  = (u16*)alloc(1048576ULL * 2);
    u16*   Wob  = (u16*)alloc(1048576ULL * 2);
    u16*   kwb  = (u16*)alloc(1048576ULL * 2);
    u16*   zb   = dbuf;
    float* hbuf = y;

    // 1) converts / splits / weight concat
    split_k<<<4096, 256, 0, stream>>>(x, xh, xl);
    wcat_k<<<1536, 256, 0, stream>>>(Wq, Wk, Wv, Wcat);
    cvt_k<<<512, 256, 0, stream>>>(fc1w, fwb);
    cvt_k<<<512, 256, 0, stream>>>(Wo, Wob);
    cvt_k<<<512, 256, 0, stream>>>(kaw, kwb);

    // 2) mn branch: 3x (diff -> BN=128 gemm8), then tail rows
    diff_k<<<8192, 256, 0, stream>>>(x, dbuf, 1);
    gemm8_k<128, 1, false><<<dim3(8, 32), 512, 0, stream>>>(
        dbuf, dbuf, dbuf, 1024, fwb, fwb, fwb, 1024,
        mn, nullptr, nullptr, fc1b, 1024, 1024, 0, 1.0f, 0);
    diff_k<<<8192, 256, 0, stream>>>(x, dbuf, 2);
    gemm8_k<128, 2, false><<<dim3(8, 32), 512, 0, stream>>>(
        dbuf, dbuf, dbuf, 1024, fwb, fwb, fwb, 1024,
        mn, nullptr, nullptr, fc1b, 1024, 1024, 0, 1.0f, 0);
    diff_k<<<8192, 256, 0, stream>>>(x, dbuf, 4);
    gemm8_k<128, 2, false><<<dim3(8, 32), 512, 0, stream>>>(
        dbuf, dbuf, dbuf, 1024, fwb, fwb, fwb, 1024,
        mn, nullptr, nullptr, fc1b, 1024, 1024, 0, 1.0f, 0);
    tail_k<<<16, 256, 0, stream>>>(x, mn);

    // 3) mega QKV: [xh|xl|xh] @ Wcat^T -> QKVh/QKVl (Q cols scaled 0.06)
    gemm8_k<256, 4, true><<<dim3(12, 32), 512, 0, stream>>>(
        xh, xl, xh, 1024, Wcat, Wcat + 1024, Wcat + 2048, 3072,
        nullptr, QKVh, QKVl, nullptr, 3072, 3072, 0, 0.06f, 1024);
    transpose_bf16<<<dim3(16, 128), 256, 0, stream>>>(QKVh + 2048, Vt, 3072, 8192);

    // 4) logits: Qh·Kh + Ql·Kh + Qh·Kl via segmented K=3072 GEMM; softmax
    for (int c = 0; c < 4; ++c) {
        const u16* Qc = QKVh + (size_t)c * 2048 * 3072;
        const u16* Ql = QKVl + (size_t)c * 2048 * 3072;
        gemm8_k<256, 0, true><<<dim3(32, 8), 512, 0, stream>>>(
            Qc, Ql, Qc, 3072, QKVh + 1024, QKVh + 1024, QKVl + 1024, 3072,
            Sf, nullptr, nullptr, nullptr, 8192, 3072, 0, 1.0f, 0);
        softmax_k<<<2048, 256, 0, stream>>>(Sf, aw, c * 2048);
    }

    // 5) ST = aw^T (bf16); y/y2 = split-K halves of ST @ Vt^T  (== aw^T @ V)
    transpose_f32_bf16<<<dim3(128, 128), 256, 0, stream>>>(aw, ST);
    gemm8_k<256, 0, false><<<dim3(4, 32, 2), 512, 0, stream>>>(
        ST, ST, ST, 8192, Vt, Vt, Vt, 8192,
        y, nullptr, nullptr, nullptr, 1024, 4096, NM, 1.0f, 0);
    cvt2_k<<<4096, 256, 0, stream>>>(y, y2, yb);

    // 6) head
    gemm8_k<128, 0, false><<<dim3(8, 32), 512, 0, stream>>>(
        yb, yb, yb, 1024, Wob, Wob, Wob, 1024,
        y2, nullptr, nullptr, nullptr, 1024, 1024, 0, 1.0f, 0);
    ln_y_k<<<8192, 256, 0, stream>>>(y2, mn, lyg, lyb, zb);
    gemm8_k<128, 1, false><<<dim3(8, 32), 512, 0, stream>>>(
        zb, zb, zb, 1024, kwb, kwb, kwb, 1024,
        hbuf, nullptr, nullptr, kab, 1024, 1024, 0, 1.0f, 0);
    ln_dot_k<<<8192, 256, 0, stream>>>(hbuf, lkg, lkb, kdw, kdb, out0);
}

// Round 5
// 1164.630 us; speedup vs baseline: 1.3751x; 1.3751x over previous
//
#include <hip/hip_runtime.h>
#include <cstdint>
#include <cstddef>

typedef unsigned short u16;
typedef short bf16x8 __attribute__((ext_vector_type(8)));
typedef float f32x4 __attribute__((ext_vector_type(4)));

#define LN_EPS 1e-6f

// async global->LDS, 16B per lane; LDS dest is wave-uniform base + lane*16
#define GLD16(gsrc, ldst) \
    __builtin_amdgcn_global_load_lds( \
        (const __attribute__((address_space(1))) void*)(gsrc), \
        (__attribute__((address_space(3))) void*)(ldst), 16, 0, 0)

__device__ inline u16 f2bf(float f) {
    uint32_t x = __float_as_uint(f);
    uint32_t r = (x + 0x7fffu + ((x >> 16) & 1u)) >> 16;   // RNE
    return (u16)r;
}
__device__ inline float bf2f(u16 u) { return __uint_as_float(((uint32_t)u) << 16); }

// ---------------- block reductions (256 threads = 4 waves) ----------------
__device__ inline float blk_sum(float v, float* s) {
    #pragma unroll
    for (int o = 32; o > 0; o >>= 1) v += __shfl_xor(v, o);
    __syncthreads();
    if ((threadIdx.x & 63) == 0) s[threadIdx.x >> 6] = v;
    __syncthreads();
    return s[0] + s[1] + s[2] + s[3];
}
__device__ inline float blk_max(float v, float* s) {
    #pragma unroll
    for (int o = 32; o > 0; o >>= 1) v = fmaxf(v, __shfl_xor(v, o));
    __syncthreads();
    if ((threadIdx.x & 63) == 0) s[threadIdx.x >> 6] = v;
    __syncthreads();
    return fmaxf(fmaxf(s[0], s[1]), fmaxf(s[2], s[3]));
}

// =====================================================================
// 8-phase 256xBN GEMM (m201-template port; R3-validated structure, no SEG).
// C[m][n] = sum_k A[m][k]*B[n][k], row-major k-contiguous.
// BN in {256,128}: 8 waves as 2(M)x4(N), per-wave 128 x BN/4.
// BK=64 staged as 2 k-halves; double-buffered LDS.
// Counted vmcnt ckpts (4 for BN=256, 3 for BN=128) at phases 2/4; never 0
// mid-loop. LDS 16B-slot swizzle applied on global SOURCE col (linear
// global_load_lds dest) and on ds_read addr (rule #21).
// Grid (N/BN, M/256, Z); Z split-K: A,B advance z*K elems, C advances
// z*zCstride floats. Requires gridDim.x*gridDim.y % 8 == 0 and exactly
// <=256 blocks per round for full-chip runs (1 block/CU at this LDS).
// MODE: 0 f32*scale | 1 f32 relu(acc+bias) | 2 f32 += relu(acc+bias)
//       | 3 bf16*scale | 4 bf16 hi/lo split store *scale
// =====================================================================
template<int BN, int MODE>
__global__ __launch_bounds__(512, 2) void gemm8_k(
    const u16* __restrict__ A, int lda, const u16* __restrict__ B, int ldb,
    float* __restrict__ Cf, u16* __restrict__ Cb, u16* __restrict__ Cb2,
    const float* __restrict__ bias, int ldc, int K, size_t zCstride, float scale)
{
    constexpr int NFRAG = BN / 64;          // n-fragments per wave
    constexpr int BKH   = BN * 32;          // B per-kh elems
    constexpr int BUFE  = 16384 + BN * 64;  // elems per buffer (A 2kh + B 2kh)
    __shared__ u16 lds[2 * BUFE];

    const int tid  = threadIdx.x;
    const int lane = tid & 63, wid = tid >> 6;
    const int wr = wid >> 2, wc = wid & 3;
    const int fr = lane & 15, fg = lane >> 4;

    const int gx  = gridDim.x, nwg = gx * gridDim.y;
    const int bid = blockIdx.y * gx + blockIdx.x;
    const int wg  = (bid & 7) * (nwg >> 3) + (bid >> 3);   // XCD-contiguous
    const int n0  = (wg % gx) * BN, m0 = (wg / gx) * 256;

    const u16* Az = A + (size_t)blockIdx.z * K;
    const u16* Bz = B + (size_t)blockIdx.z * K;
    float* Cfz = Cf ? Cf + (size_t)blockIdx.z * zCstride : nullptr;

    // staging geometry: thread covers row sr (and sr+128 for 256-row tiles)
    const int sr = tid >> 2;
    const int kb = ((tid & 3) ^ ((sr >> 1) & 3)) * 8;   // pre-swizzled col

    f32x4 acc[8][NFRAG];
    {
        f32x4 z = {0.f, 0.f, 0.f, 0.f};
        #pragma unroll
        for (int m = 0; m < 8; m++)
            #pragma unroll
            for (int n = 0; n < NFRAG; n++) acc[m][n] = z;
    }

    const int NT = K >> 6;

    auto STAGE = [&](int buf, int isB, int kh, int kt) {
        const u16* s0 = isB ? Bz : Az;
        const int  ld = isB ? ldb : lda;
        const int  rb = isB ? n0 : m0;
        const int  k0 = kt * 64 + kh * 32 + kb;
        u16* dst = &lds[buf * BUFE + (isB ? 16384 : 0) + kh * (isB ? BKH : 8192) + tid * 8];
        GLD16(s0 + (size_t)(rb + sr) * ld + k0, dst);
        if (!isB || BN == 256)
            GLD16(s0 + (size_t)(rb + 128 + sr) * ld + k0, dst + 4096);
    };

    #define CKPT_MID() do { if constexpr (BN == 256) asm volatile("s_waitcnt vmcnt(4)" ::: "memory"); \
                            else                     asm volatile("s_waitcnt vmcnt(3)" ::: "memory"); } while (0)

    // per-lane read bases (u16 units)
    const int swz   = (fg ^ ((fr >> 1) & 3)) * 8;
    const int baseA = (wr * 128 + fr) * 32 + swz;
    const int baseB = 16384 + (wc * (BN / 4) + fr) * 32 + swz;

    // prologue: A-kh0, B-kh0, A-kh1, B-kh1 of tile 0
    STAGE(0, 0, 0, 0); STAGE(0, 1, 0, 0); STAGE(0, 0, 1, 0); STAGE(0, 1, 1, 0);
    CKPT_MID();                                            // kh0 group landed
    __builtin_amdgcn_s_barrier();

    bf16x8 af[4], bv[NFRAG];

    for (int t = 0; t < NT; ++t) {
        const int  aO  = (t & 1) * BUFE;
        const int  nxt = (t & 1) ^ 1;
        const bool pre = (t + 1 < NT);

        // ---- phase 1: (ms=0, ks=0)
        #pragma unroll
        for (int m = 0; m < 4; m++) af[m] = *(const bf16x8*)&lds[baseA + aO + m * 512];
        #pragma unroll
        for (int n = 0; n < NFRAG; n++) bv[n] = *(const bf16x8*)&lds[baseB + aO + n * 512];
        if (pre) STAGE(nxt, 0, 0, t + 1);
        __builtin_amdgcn_s_barrier();
        asm volatile("s_waitcnt lgkmcnt(0)" ::: "memory");
        __builtin_amdgcn_sched_barrier(0);
        __builtin_amdgcn_s_setprio(1);
        #pragma unroll
        for (int m = 0; m < 4; m++)
            #pragma unroll
            for (int n = 0; n < NFRAG; n++)
                acc[m][n] = __builtin_amdgcn_mfma_f32_16x16x32_bf16(af[m], bv[n], acc[m][n], 0, 0, 0);
        __builtin_amdgcn_s_setprio(0);
        __builtin_amdgcn_s_barrier();

        // ---- phase 2: (ms=1, ks=0); ckpt kh1(t)
        #pragma unroll
        for (int m = 0; m < 4; m++) af[m] = *(const bf16x8*)&lds[baseA + aO + (4 + m) * 512];
        if (pre) STAGE(nxt, 1, 0, t + 1);
        __builtin_amdgcn_s_barrier();
        asm volatile("s_waitcnt lgkmcnt(0)" ::: "memory");
        __builtin_amdgcn_sched_barrier(0);
        __builtin_amdgcn_s_setprio(1);
        #pragma unroll
        for (int m = 0; m < 4; m++)
            #pragma unroll
            for (int n = 0; n < NFRAG; n++)
                acc[4 + m][n] = __builtin_amdgcn_mfma_f32_16x16x32_bf16(af[m], bv[n], acc[4 + m][n], 0, 0, 0);
        __builtin_amdgcn_s_setprio(0);
        if (pre) { CKPT_MID(); }
        else     { asm volatile("s_waitcnt vmcnt(0)" ::: "memory"); }
        __builtin_amdgcn_sched_barrier(0);
        __builtin_amdgcn_s_barrier();

        // ---- phase 3: (ms=0, ks=1)
        #pragma unroll
        for (int m = 0; m < 4; m++) af[m] = *(const bf16x8*)&lds[baseA + aO + 8192 + m * 512];
        #pragma unroll
        for (int n = 0; n < NFRAG; n++) bv[n] = *(const bf16x8*)&lds[baseB + aO + BKH + n * 512];
        if (pre) STAGE(nxt, 0, 1, t + 1);
        __builtin_amdgcn_s_barrier();
        asm volatile("s_waitcnt lgkmcnt(0)" ::: "memory");
        __builtin_amdgcn_sched_barrier(0);
        __builtin_amdgcn_s_setprio(1);
        #pragma unroll
        for (int m = 0; m < 4; m++)
            #pragma unroll
            for (int n = 0; n < NFRAG; n++)
                acc[m][n] = __builtin_amdgcn_mfma_f32_16x16x32_bf16(af[m], bv[n], acc[m][n], 0, 0, 0);
        __builtin_amdgcn_s_setprio(0);
        __builtin_amdgcn_s_barrier();

        // ---- phase 4: (ms=1, ks=1); ckpt kh0(t+1)
        #pragma unroll
        for (int m = 0; m < 4; m++) af[m] = *(const bf16x8*)&lds[baseA + aO + 8192 + (4 + m) * 512];
        if (pre) STAGE(nxt, 1, 1, t + 1);
        __builtin_amdgcn_s_barrier();
        asm volatile("s_waitcnt lgkmcnt(0)" ::: "memory");
        __builtin_amdgcn_sched_barrier(0);
        __builtin_amdgcn_s_setprio(1);
        #pragma unroll
        for (int m = 0; m < 4; m++)
            #pragma unroll
            for (int n = 0; n < NFRAG; n++)
                acc[4 + m][n] = __builtin_amdgcn_mfma_f32_16x16x32_bf16(af[m], bv[n], acc[4 + m][n], 0, 0, 0);
        __builtin_amdgcn_s_setprio(0);
        if (pre) { CKPT_MID(); }
        __builtin_amdgcn_sched_barrier(0);
        __builtin_amdgcn_s_barrier();
    }
    #undef CKPT_MID

    // epilogue: D layout col = lane&15, row = (lane>>4)*4 + reg [HW-verified]
    #pragma unroll
    for (int m = 0; m < 8; m++)
        #pragma unroll
        for (int n = 0; n < NFRAG; n++)
            #pragma unroll
            for (int r = 0; r < 4; r++) {
                int row = m0 + wr * 128 + m * 16 + fg * 4 + r;
                int col = n0 + wc * (BN / 4) + n * 16 + fr;
                size_t idx = (size_t)row * ldc + col;
                float v = acc[m][n][r] * scale;
                if (MODE == 0) {
                    Cfz[idx] = v;
                } else if (MODE == 1) {
                    Cfz[idx] = fmaxf(v + bias[col], 0.f);
                } else if (MODE == 2) {
                    Cfz[idx] += fmaxf(v + bias[col], 0.f);
                } else if (MODE == 3) {
                    Cb[idx] = f2bf(v);
                } else {
                    u16 h = f2bf(v);
                    Cb[idx]  = h;
                    Cb2[idx] = f2bf(v - bf2f(h));
                }
            }
}

// ---------------- elementwise / converts ----------------
__global__ __launch_bounds__(256) void split_k(const float* __restrict__ s,
                                               u16* __restrict__ hi, u16* __restrict__ lo) {
    int i = blockIdx.x * 256 + threadIdx.x;
    const float4* sf = reinterpret_cast<const float4*>(s);
    float4 a = sf[2 * i], b = sf[2 * i + 1];
    float vals[8] = {a.x, a.y, a.z, a.w, b.x, b.y, b.z, b.w};
    union { u16 u[8]; int4 v; } th, tl;
    #pragma unroll
    for (int k = 0; k < 8; k++) {
        u16 h = f2bf(vals[k]);
        th.u[k] = h;
        tl.u[k] = f2bf(vals[k] - bf2f(h));
    }
    reinterpret_cast<int4*>(hi)[i] = th.v;
    reinterpret_cast<int4*>(lo)[i] = tl.v;
}

// W (1024x1024 f32) -> Wcat (1024x3072 bf16): cols [h | h | l]
__global__ __launch_bounds__(256) void wsplit3_k(const float* __restrict__ W,
                                                 u16* __restrict__ out) {
    int i = blockIdx.x * 256 + threadIdx.x;    // 131072: 1024 rows x 128 chunks
    int r = i >> 7, c8 = i & 127;
    const float* src = W + (size_t)r * 1024 + c8 * 8;
    float4 a = *reinterpret_cast<const float4*>(src);
    float4 b = *reinterpret_cast<const float4*>(src + 4);
    float vals[8] = {a.x, a.y, a.z, a.w, b.x, b.y, b.z, b.w};
    union { u16 u[8]; int4 v; } th, tl;
    #pragma unroll
    for (int k = 0; k < 8; k++) {
        u16 h = f2bf(vals[k]);
        th.u[k] = h;
        tl.u[k] = f2bf(vals[k] - bf2f(h));
    }
    u16* drow = out + (size_t)r * 3072 + c8 * 8;
    *reinterpret_cast<int4*>(drow)        = th.v;
    *reinterpret_cast<int4*>(drow + 1024) = th.v;
    *reinterpret_cast<int4*>(drow + 2048) = tl.v;
}

__global__ __launch_bounds__(256) void cvt_k(const float* __restrict__ s, u16* __restrict__ d) {
    int i = blockIdx.x * 256 + threadIdx.x;
    const float4* sf = reinterpret_cast<const float4*>(s);
    float4 a = sf[2 * i], b = sf[2 * i + 1];
    union { u16 u[8]; int4 v; } t;
    t.u[0] = f2bf(a.x); t.u[1] = f2bf(a.y); t.u[2] = f2bf(a.z); t.u[3] = f2bf(a.w);
    t.u[4] = f2bf(b.x); t.u[5] = f2bf(b.y); t.u[6] = f2bf(b.z); t.u[7] = f2bf(b.w);
    reinterpret_cast<int4*>(d)[i] = t.v;
}

// yb = bf16(y + y2)  (split-K PV reduction fused into the convert)
__global__ __launch_bounds__(256) void cvt2_k(const float* __restrict__ s0, const float* __restrict__ s1,
                                              u16* __restrict__ d) {
    int i = blockIdx.x * 256 + threadIdx.x;
    const float4* f0 = reinterpret_cast<const float4*>(s0);
    const float4* f1 = reinterpret_cast<const float4*>(s1);
    float4 a = f0[2 * i], b = f0[2 * i + 1];
    float4 c = f1[2 * i], e = f1[2 * i + 1];
    union { u16 u[8]; int4 v; } t;
    t.u[0] = f2bf(a.x + c.x); t.u[1] = f2bf(a.y + c.y);
    t.u[2] = f2bf(a.z + c.z); t.u[3] = f2bf(a.w + c.w);
    t.u[4] = f2bf(b.x + e.x); t.u[5] = f2bf(b.y + e.y);
    t.u[6] = f2bf(b.z + e.z); t.u[7] = f2bf(b.w + e.w);
    reinterpret_cast<int4*>(d)[i] = t.v;
}

// dst rows = [s0 | s1 | s2] (each 8192x1024 bf16 -> 8192x3072)
__global__ __launch_bounds__(256) void cat3_k(const u16* __restrict__ s0, const u16* __restrict__ s1,
                                              const u16* __restrict__ s2, u16* __restrict__ dst) {
    int i = blockIdx.x * 256 + threadIdx.x;     // int4-chunk id: 8192 rows x 128 chunks
    int r = i >> 7, c8 = i & 127;
    const int4* p0 = reinterpret_cast<const int4*>(s0 + (size_t)r * 1024);
    const int4* p1 = reinterpret_cast<const int4*>(s1 + (size_t)r * 1024);
    const int4* p2 = reinterpret_cast<const int4*>(s2 + (size_t)r * 1024);
    int4* d = reinterpret_cast<int4*>(dst + (size_t)r * 3072);
    d[c8]       = p0[c8];
    d[c8 + 128] = p1[c8];
    d[c8 + 256] = p2[c8];
}

// dbuf[i][:] = bf16(|x[i+shift][:] - x[i][:]|) for i<8188, else 0
__global__ __launch_bounds__(256) void diff_k(const float* __restrict__ x, u16* __restrict__ d, int shift) {
    int i4 = blockIdx.x * 256 + threadIdx.x;
    int row = i4 >> 8;
    const float4* xf = reinterpret_cast<const float4*>(x);
    ushort4 o;
    if (row < 8188) {
        float4 a = xf[i4 + (shift << 8)];
        float4 b = xf[i4];
        o.x = f2bf(fabsf(a.x - b.x));
        o.y = f2bf(fabsf(a.y - b.y));
        o.z = f2bf(fabsf(a.z - b.z));
        o.w = f2bf(fabsf(a.w - b.w));
    } else {
        o.x = o.y = o.z = o.w = 0;
    }
    reinterpret_cast<ushort4*>(d)[i4] = o;
}

__global__ __launch_bounds__(256) void tail_k(const float* __restrict__ x, float* __restrict__ mn) {
    int i = blockIdx.x * 256 + threadIdx.x;
    mn[8188 * 1024 + i] = x[8188 * 1024 + i];
}

// ---------------- softmax over a row of 8192 fp32 ----------------
__global__ __launch_bounds__(256) void softmax_k(const float* __restrict__ S,
                                                 float* __restrict__ aw, int row0) {
    __shared__ float red[4];
    int r = blockIdx.x, tid = threadIdx.x;
    const float4* src = reinterpret_cast<const float4*>(S + (size_t)r * 8192);
    float4 xv[8];
    float mx = -1e30f;
    #pragma unroll
    for (int j = 0; j < 8; j++) {
        xv[j] = src[tid + 256 * j];
        mx = fmaxf(mx, fmaxf(fmaxf(xv[j].x, xv[j].y), fmaxf(xv[j].z, xv[j].w)));
    }
    mx = blk_max(mx, red);
    float sum = 0.f;
    #pragma unroll
    for (int j = 0; j < 8; j++) {
        xv[j].x = __expf(xv[j].x - mx); sum += xv[j].x;
        xv[j].y = __expf(xv[j].y - mx); sum += xv[j].y;
        xv[j].z = __expf(xv[j].z - mx); sum += xv[j].z;
        xv[j].w = __expf(xv[j].w - mx); sum += xv[j].w;
    }
    sum = blk_sum(sum, red);
    float inv = 1.0f / sum;
    float4* dst = reinterpret_cast<float4*>(aw + (size_t)(row0 + r) * 8192);
    #pragma unroll
    for (int j = 0; j < 8; j++) {
        float4 o;
        o.x = xv[j].x * inv; o.y = xv[j].y * inv; o.z = xv[j].z * inv; o.w = xv[j].w * inv;
        dst[tid + 256 * j] = o;
    }
}

// ---------------- transposes (64x64 tiles) ----------------
__global__ __launch_bounds__(256) void transpose_f32_bf16(const float* __restrict__ src,
                                                          u16* __restrict__ dst) {
    __shared__ u16 t[64][72];
    int r0 = blockIdx.y * 64, c0 = blockIdx.x * 64;
    int tid = threadIdx.x;
    #pragma unroll
    for (int p = 0; p < 4; p++) {
        int q = p * 256 + tid;
        int r = q >> 4, c4 = q & 15;
        float4 v = *(reinterpret_cast<const float4*>(src + (size_t)(r0 + r) * 8192 + c0) + c4);
        t[c4 * 4 + 0][r] = f2bf(v.x);
        t[c4 * 4 + 1][r] = f2bf(v.y);
        t[c4 * 4 + 2][r] = f2bf(v.z);
        t[c4 * 4 + 3][r] = f2bf(v.w);
    }
    __syncthreads();
    #pragma unroll
    for (int p = 0; p < 2; p++) {
        int q = p * 256 + tid;
        int rr = q >> 3, cc = q & 7;
        *reinterpret_cast<int4*>(dst + (size_t)(c0 + rr) * 8192 + r0 + cc * 8) =
            *reinterpret_cast<const int4*>(&t[rr][cc * 8]);
    }
}

// bf16 transpose with leading dims; grid (srccols/64, srcrows/64)
__global__ __launch_bounds__(256) void transpose_bf16(const u16* __restrict__ src,
                                                      u16* __restrict__ dst,
                                                      int srcld, int dstld) {
    __shared__ u16 t[64][72];
    int r0 = blockIdx.y * 64, c0 = blockIdx.x * 64;
    int tid = threadIdx.x;
    #pragma unroll
    for (int p = 0; p < 2; p++) {
        int q = p * 256 + tid;
        int r = q >> 3, c8 = q & 7;
        int4 v = *(reinterpret_cast<const int4*>(src + (size_t)(r0 + r) * srcld + c0) + c8);
        const u16* u = reinterpret_cast<const u16*>(&v);
        #pragma unroll
        for (int k = 0; k < 8; k++) t[c8 * 8 + k][r] = u[k];
    }
    __syncthreads();
    #pragma unroll
    for (int p = 0; p < 2; p++) {
        int q = p * 256 + tid;
        int rr = q >> 3, cc = q & 7;
        *reinterpret_cast<int4*>(dst + (size_t)(c0 + rr) * dstld + r0 + cc * 8) =
            *reinterpret_cast<const int4*>(&t[rr][cc * 8]);
    }
}

// ---------------- LN kernels ----------------
__global__ __launch_bounds__(256) void ln_y_k(const float* __restrict__ y2, const float* __restrict__ mn,
                                              const float* __restrict__ g, const float* __restrict__ b,
                                              u16* __restrict__ zb) {
    __shared__ float red[4];
    int r = blockIdx.x, tid = threadIdx.x;
    float4 a = reinterpret_cast<const float4*>(y2 + (size_t)r * 1024)[tid];
    float4 c = reinterpret_cast<const float4*>(mn + (size_t)r * 1024)[tid];
    float4 v; v.x = a.x + c.x; v.y = a.y + c.y; v.z = a.z + c.z; v.w = a.w + c.w;
    float s  = v.x + v.y + v.z + v.w;
    float sq = v.x * v.x + v.y * v.y + v.z * v.z + v.w * v.w;
    s  = blk_sum(s, red);
    sq = blk_sum(sq, red);
    float mu = s * (1.0f / 1024.0f);
    float rs = rsqrtf(sq * (1.0f / 1024.0f) - mu * mu + LN_EPS);
    float4 gg = reinterpret_cast<const float4*>(g)[tid];
    float4 bb = reinterpret_cast<const float4*>(b)[tid];
    ushort4 o;
    o.x = f2bf((v.x - mu) * rs * gg.x + bb.x);
    o.y = f2bf((v.y - mu) * rs * gg.y + bb.y);
    o.z = f2bf((v.z - mu) * rs * gg.z + bb.z);
    o.w = f2bf((v.w - mu) * rs * gg.w + bb.w);
    reinterpret_cast<ushort4*>(zb + (size_t)r * 1024)[tid] = o;
}

__global__ __launch_bounds__(256) void ln_dot_k(const float* __restrict__ h, const float* __restrict__ g,
                                                const float* __restrict__ b, const float* __restrict__ kd,
                                                const float* __restrict__ kdb, float* __restrict__ out) {
    __shared__ float red[4];
    int r = blockIdx.x, tid = threadIdx.x;
    float4 v = reinterpret_cast<const float4*>(h + (size_t)r * 1024)[tid];
    float s  = v.x + v.y + v.z + v.w;
    float sq = v.x * v.x + v.y * v.y + v.z * v.z + v.w * v.w;
    s  = blk_sum(s, red);
    sq = blk_sum(sq, red);
    float mu = s * (1.0f / 1024.0f);
    float rs = rsqrtf(sq * (1.0f / 1024.0f) - mu * mu + LN_EPS);
    float4 gg = reinterpret_cast<const float4*>(g)[tid];
    float4 bb = reinterpret_cast<const float4*>(b)[tid];
    float4 kk = reinterpret_cast<const float4*>(kd)[tid];
    float part = ((v.x - mu) * rs * gg.x + bb.x) * kk.x
               + ((v.y - mu) * rs * gg.y + bb.y) * kk.y
               + ((v.z - mu) * rs * gg.z + bb.z) * kk.z
               + ((v.w - mu) * rs * gg.w + bb.w) * kk.w;
    part = blk_sum(part, red);
    if (tid == 0) out[r] = 1.0f / (1.0f + __expf(-(part + kdb[0])));
}

// ---------------- launch ----------------
extern "C" void kernel_launch(void* const* d_in, const int* in_sizes, int n_in,
                              void* d_out, int out_size, void* d_ws, size_t ws_size,
                              hipStream_t stream) {
    (void)in_sizes; (void)n_in; (void)out_size; (void)ws_size;
    const float* x    = (const float*)d_in[0];
    const float* Wq   = (const float*)d_in[2];
    const float* Wk   = (const float*)d_in[3];
    const float* Wv   = (const float*)d_in[4];
    const float* Wo   = (const float*)d_in[5];
    const float* fc1w = (const float*)d_in[6];
    const float* fc1b = (const float*)d_in[7];
    const float* kaw  = (const float*)d_in[8];
    const float* kab  = (const float*)d_in[9];
    const float* kdw  = (const float*)d_in[10];
    const float* kdb  = (const float*)d_in[11];
    const float* lyg  = (const float*)d_in[12];
    const float* lyb  = (const float*)d_in[13];
    const float* lkg  = (const float*)d_in[14];
    const float* lkb  = (const float*)d_in[15];

    float* out0 = (float*)d_out;
    float* aw   = out0 + 8192;

    char* base = (char*)d_ws;
    size_t off = 0;
    auto alloc = [&](size_t bytes) -> char* {
        char* p = base + off;
        off += (bytes + 255) & ~(size_t)255;
        return p;
    };
    const size_t NM = 8192ULL * 1024ULL;
    u16*   ST   = (u16*)alloc(8192ULL * 8192ULL * 2);   // 128MB; 1st half = Sf, 2nd half hosts xcat
    float* Sf   = (float*)ST;                           // 2048x8192 fp32 chunk (64MB)
    u16*   xcat = ST + 33554432ULL;                     // 8192x3072 bf16 (48MB) in ST 2nd half
    u16*   xh   = (u16*)alloc(NM * 2);
    u16*   xl   = (u16*)alloc(NM * 2);
    u16*   qh   = (u16*)alloc(NM * 2);
    u16*   ql   = (u16*)alloc(NM * 2);
    u16*   kh   = (u16*)alloc(NM * 2);
    u16*   kl   = (u16*)alloc(NM * 2);
    u16*   Vb   = (u16*)alloc(NM * 2);
    u16*   Vt   = (u16*)alloc(NM * 2);
    u16*   dbuf = (u16*)alloc(NM * 2);                  // later reused as zb
    u16*   yb   = (u16*)alloc(NM * 2);
    float* mn   = (float*)alloc(NM * 4);
    float* y    = (float*)alloc(NM * 4);                // later reused as h; Qcat aliases y..y2
    float* y2   = (float*)alloc(NM * 4);                // y2 == y + NM (256B-aligned sizes)
    u16*   Wqc  = (u16*)alloc(1024ULL * 3072ULL * 2);   // [Wqh|Wqh|Wql]
    u16*   Wkc  = (u16*)alloc(1024ULL * 3072ULL * 2);   // [Wkh|Wkh|Wkl]
    u16*   Wvb  = (u16*)alloc(1048576ULL * 2);
    u16*   fwb  = (u16*)alloc(1048576ULL * 2);
    u16*   Wob  = (u16*)alloc(1048576ULL * 2);
    u16*   kwb  = (u16*)alloc(1048576ULL * 2);
    u16*   Kcat = (u16*)alloc(8192ULL * 3072ULL * 2);   // 48MB
    u16*   Qcat = (u16*)y;                              // 48MB alias over y+y2 (dead before PV)
    u16*   zb   = dbuf;
    float* hbuf = y;

    // 1) converts / splits
    split_k<<<4096, 256, 0, stream>>>(x, xh, xl);
    wsplit3_k<<<512, 256, 0, stream>>>(Wq, Wqc);
    wsplit3_k<<<512, 256, 0, stream>>>(Wk, Wkc);
    cvt_k<<<512, 256, 0, stream>>>(Wv, Wvb);
    cvt_k<<<512, 256, 0, stream>>>(fc1w, fwb);
    cvt_k<<<512, 256, 0, stream>>>(Wo, Wob);
    cvt_k<<<512, 256, 0, stream>>>(kaw, kwb);

    // 2) mn branch: 3x (diff -> BN=128 gemm8), then tail rows
    diff_k<<<8192, 256, 0, stream>>>(x, dbuf, 1);
    gemm8_k<128, 1><<<dim3(8, 32), 512, 0, stream>>>(
        dbuf, 1024, fwb, 1024, mn, nullptr, nullptr, fc1b, 1024, 1024, 0, 1.0f);
    diff_k<<<8192, 256, 0, stream>>>(x, dbuf, 2);
    gemm8_k<128, 2><<<dim3(8, 32), 512, 0, stream>>>(
        dbuf, 1024, fwb, 1024, mn, nullptr, nullptr, fc1b, 1024, 1024, 0, 1.0f);
    diff_k<<<8192, 256, 0, stream>>>(x, dbuf, 4);
    gemm8_k<128, 2><<<dim3(8, 32), 512, 0, stream>>>(
        dbuf, 1024, fwb, 1024, mn, nullptr, nullptr, fc1b, 1024, 1024, 0, 1.0f);
    tail_k<<<16, 256, 0, stream>>>(x, mn);

    // 3) projections: xcat=[xh|xl|xh]; Q/K via K=3072 split GEMMs; V plain
    cat3_k<<<4096, 256, 0, stream>>>(xh, xl, xh, xcat);
    gemm8_k<128, 4><<<dim3(8, 32), 512, 0, stream>>>(
        xcat, 3072, Wqc, 3072, nullptr, qh, ql, nullptr, 1024, 3072, 0, 0.06f);
    gemm8_k<128, 4><<<dim3(8, 32), 512, 0, stream>>>(
        xcat, 3072, Wkc, 3072, nullptr, kh, kl, nullptr, 1024, 3072, 0, 1.0f);
    gemm8_k<128, 3><<<dim3(8, 32), 512, 0, stream>>>(
        xh, 1024, Wvb, 1024, nullptr, Vb, nullptr, nullptr, 1024, 1024, 0, 1.0f);
    transpose_bf16<<<dim3(16, 128), 256, 0, stream>>>(Vb, Vt, 1024, 8192);
    cat3_k<<<4096, 256, 0, stream>>>(qh, ql, qh, Qcat);   // [Qh|Ql|Qh]
    cat3_k<<<4096, 256, 0, stream>>>(kh, kh, kl, Kcat);   // [Kh|Kh|Kl]

    // 4) logits via K=3072 concat GEMM (== QhKh+QlKh+QhKl) + softmax
    for (int c = 0; c < 4; ++c) {
        gemm8_k<256, 0><<<dim3(32, 8), 512, 0, stream>>>(
            Qcat + (size_t)c * 2048 * 3072, 3072, Kcat, 3072,
            Sf, nullptr, nullptr, nullptr, 8192, 3072, 0, 1.0f);
        softmax_k<<<2048, 256, 0, stream>>>(Sf, aw, c * 2048);
    }

    // 5) ST = aw^T (bf16); y/y2 = split-K halves of ST @ Vt^T  (== aw^T @ V)
    transpose_f32_bf16<<<dim3(128, 128), 256, 0, stream>>>(aw, ST);
    gemm8_k<256, 0><<<dim3(4, 32, 2), 512, 0, stream>>>(
        ST, 8192, Vt, 8192, y, nullptr, nullptr, nullptr, 1024, 4096, NM, 1.0f);
    cvt2_k<<<4096, 256, 0, stream>>>(y, y2, yb);

    // 6) head
    gemm8_k<128, 0><<<dim3(8, 32), 512, 0, stream>>>(
        yb, 1024, Wob, 1024, y2, nullptr, nullptr, nullptr, 1024, 1024, 0, 1.0f);
    ln_y_k<<<8192, 256, 0, stream>>>(y2, mn, lyg, lyb, zb);
    gemm8_k<128, 1><<<dim3(8, 32), 512, 0, stream>>>(
        zb, 1024, kwb, 1024, hbuf, nullptr, nullptr, kab, 1024, 1024, 0, 1.0f);
    ln_dot_k<<<8192, 256, 0, stream>>>(hbuf, lkg, lkb, kdw, kdb, out0);
}

// Round 6
// 969.641 us; speedup vs baseline: 1.6516x; 1.2011x over previous
//
#include <hip/hip_runtime.h>
#include <cstdint>
#include <cstddef>

typedef unsigned short u16;
typedef short bf16x8 __attribute__((ext_vector_type(8)));
typedef float f32x4 __attribute__((ext_vector_type(4)));

#define LN_EPS 1e-6f

// async global->LDS, 16B per lane; LDS dest is wave-uniform base + lane*16
#define GLD16(gsrc, ldst) \
    __builtin_amdgcn_global_load_lds( \
        (const __attribute__((address_space(1))) void*)(gsrc), \
        (__attribute__((address_space(3))) void*)(ldst), 16, 0, 0)

__device__ inline u16 f2bf(float f) {
    uint32_t x = __float_as_uint(f);
    uint32_t r = (x + 0x7fffu + ((x >> 16) & 1u)) >> 16;   // RNE
    return (u16)r;
}
__device__ inline float bf2f(u16 u) { return __uint_as_float(((uint32_t)u) << 16); }

// ---------------- block reductions (256 threads = 4 waves) ----------------
__device__ inline float blk_sum(float v, float* s) {
    #pragma unroll
    for (int o = 32; o > 0; o >>= 1) v += __shfl_xor(v, o);
    __syncthreads();
    if ((threadIdx.x & 63) == 0) s[threadIdx.x >> 6] = v;
    __syncthreads();
    return s[0] + s[1] + s[2] + s[3];
}
__device__ inline float blk_max(float v, float* s) {
    #pragma unroll
    for (int o = 32; o > 0; o >>= 1) v = fmaxf(v, __shfl_xor(v, o));
    __syncthreads();
    if ((threadIdx.x & 63) == 0) s[threadIdx.x >> 6] = v;
    __syncthreads();
    return fmaxf(fmaxf(s[0], s[1]), fmaxf(s[2], s[3]));
}

// =====================================================================
// 8-phase 256xBN GEMM (m201-template port; R3/R5-validated structure).
// C[m][n] = sum_k A[m][k]*B[n][k], row-major k-contiguous.
// BN in {256,128}: 8 waves as 2(M)x4(N), per-wave 128 x BN/4.
// BK=64 staged as 2 k-halves; double-buffered LDS; counted vmcnt ckpts
// (4 for BN=256, 3 for BN=128) at phases 2/4 — never drain-0 mid-loop.
// LDS 16B-slot swizzle on global SOURCE col + ds_read addr (rule #21).
// Grid (N/BN, M/256); requires gridDim.x*gridDim.y % 8 == 0; 128/96 KiB
// LDS -> 1 block/CU, so use exactly 256 blocks for full-chip dispatches.
// MODE: 0 f32*scale | 1 f32 relu(acc+bias) | 2 f32 += relu(acc+bias)
//       | 3 bf16*scale | 4 bf16 hi/lo split (Cb/Cb2) | 5 bf16 dup to
//       idx and idx+1024 (for [kh|kh] layout)
// =====================================================================
template<int BN, int MODE>
__global__ __launch_bounds__(512, 2) void gemm8_k(
    const u16* __restrict__ A, int lda, const u16* __restrict__ B, int ldb,
    float* __restrict__ Cf, u16* __restrict__ Cb, u16* __restrict__ Cb2,
    const float* __restrict__ bias, int ldc, int K, float scale)
{
    constexpr int NFRAG = BN / 64;          // n-fragments per wave
    constexpr int BKH   = BN * 32;          // B per-kh elems
    constexpr int BUFE  = 16384 + BN * 64;  // elems per buffer (A 2kh + B 2kh)
    __shared__ u16 lds[2 * BUFE];

    const int tid  = threadIdx.x;
    const int lane = tid & 63, wid = tid >> 6;
    const int wr = wid >> 2, wc = wid & 3;
    const int fr = lane & 15, fg = lane >> 4;

    const int gx  = gridDim.x, nwg = gx * gridDim.y;
    const int bid = blockIdx.y * gx + blockIdx.x;
    const int wg  = (bid & 7) * (nwg >> 3) + (bid >> 3);   // XCD-contiguous
    const int n0  = (wg % gx) * BN, m0 = (wg / gx) * 256;

    // staging geometry: thread covers row sr (and sr+128 for 256-row tiles)
    const int sr = tid >> 2;
    const int kb = ((tid & 3) ^ ((sr >> 1) & 3)) * 8;   // pre-swizzled col

    f32x4 acc[8][NFRAG];
    {
        f32x4 z = {0.f, 0.f, 0.f, 0.f};
        #pragma unroll
        for (int m = 0; m < 8; m++)
            #pragma unroll
            for (int n = 0; n < NFRAG; n++) acc[m][n] = z;
    }

    const int NT = K >> 6;

    auto STAGE = [&](int buf, int isB, int kh, int kt) {
        const u16* s0 = isB ? B : A;
        const int  ld = isB ? ldb : lda;
        const int  rb = isB ? n0 : m0;
        const int  k0 = kt * 64 + kh * 32 + kb;
        u16* dst = &lds[buf * BUFE + (isB ? 16384 : 0) + kh * (isB ? BKH : 8192) + tid * 8];
        GLD16(s0 + (size_t)(rb + sr) * ld + k0, dst);
        if (!isB || BN == 256)
            GLD16(s0 + (size_t)(rb + 128 + sr) * ld + k0, dst + 4096);
    };

    #define CKPT_MID() do { if constexpr (BN == 256) asm volatile("s_waitcnt vmcnt(4)" ::: "memory"); \
                            else                     asm volatile("s_waitcnt vmcnt(3)" ::: "memory"); } while (0)

    // per-lane read bases (u16 units)
    const int swz   = (fg ^ ((fr >> 1) & 3)) * 8;
    const int baseA = (wr * 128 + fr) * 32 + swz;
    const int baseB = 16384 + (wc * (BN / 4) + fr) * 32 + swz;

    // prologue: A-kh0, B-kh0, A-kh1, B-kh1 of tile 0
    STAGE(0, 0, 0, 0); STAGE(0, 1, 0, 0); STAGE(0, 0, 1, 0); STAGE(0, 1, 1, 0);
    CKPT_MID();                                            // kh0 group landed
    __builtin_amdgcn_s_barrier();

    bf16x8 af[4], bv[NFRAG];

    for (int t = 0; t < NT; ++t) {
        const int  aO  = (t & 1) * BUFE;
        const int  nxt = (t & 1) ^ 1;
        const bool pre = (t + 1 < NT);

        // ---- phase 1: (ms=0, ks=0)
        #pragma unroll
        for (int m = 0; m < 4; m++) af[m] = *(const bf16x8*)&lds[baseA + aO + m * 512];
        #pragma unroll
        for (int n = 0; n < NFRAG; n++) bv[n] = *(const bf16x8*)&lds[baseB + aO + n * 512];
        if (pre) STAGE(nxt, 0, 0, t + 1);
        __builtin_amdgcn_s_barrier();
        asm volatile("s_waitcnt lgkmcnt(0)" ::: "memory");
        __builtin_amdgcn_sched_barrier(0);
        __builtin_amdgcn_s_setprio(1);
        #pragma unroll
        for (int m = 0; m < 4; m++)
            #pragma unroll
            for (int n = 0; n < NFRAG; n++)
                acc[m][n] = __builtin_amdgcn_mfma_f32_16x16x32_bf16(af[m], bv[n], acc[m][n], 0, 0, 0);
        __builtin_amdgcn_s_setprio(0);
        __builtin_amdgcn_s_barrier();

        // ---- phase 2: (ms=1, ks=0); ckpt kh1(t)
        #pragma unroll
        for (int m = 0; m < 4; m++) af[m] = *(const bf16x8*)&lds[baseA + aO + (4 + m) * 512];
        if (pre) STAGE(nxt, 1, 0, t + 1);
        __builtin_amdgcn_s_barrier();
        asm volatile("s_waitcnt lgkmcnt(0)" ::: "memory");
        __builtin_amdgcn_sched_barrier(0);
        __builtin_amdgcn_s_setprio(1);
        #pragma unroll
        for (int m = 0; m < 4; m++)
            #pragma unroll
            for (int n = 0; n < NFRAG; n++)
                acc[4 + m][n] = __builtin_amdgcn_mfma_f32_16x16x32_bf16(af[m], bv[n], acc[4 + m][n], 0, 0, 0);
        __builtin_amdgcn_s_setprio(0);
        if (pre) { CKPT_MID(); }
        else     { asm volatile("s_waitcnt vmcnt(0)" ::: "memory"); }
        __builtin_amdgcn_sched_barrier(0);
        __builtin_amdgcn_s_barrier();

        // ---- phase 3: (ms=0, ks=1)
        #pragma unroll
        for (int m = 0; m < 4; m++) af[m] = *(const bf16x8*)&lds[baseA + aO + 8192 + m * 512];
        #pragma unroll
        for (int n = 0; n < NFRAG; n++) bv[n] = *(const bf16x8*)&lds[baseB + aO + BKH + n * 512];
        if (pre) STAGE(nxt, 0, 1, t + 1);
        __builtin_amdgcn_s_barrier();
        asm volatile("s_waitcnt lgkmcnt(0)" ::: "memory");
        __builtin_amdgcn_sched_barrier(0);
        __builtin_amdgcn_s_setprio(1);
        #pragma unroll
        for (int m = 0; m < 4; m++)
            #pragma unroll
            for (int n = 0; n < NFRAG; n++)
                acc[m][n] = __builtin_amdgcn_mfma_f32_16x16x32_bf16(af[m], bv[n], acc[m][n], 0, 0, 0);
        __builtin_amdgcn_s_setprio(0);
        __builtin_amdgcn_s_barrier();

        // ---- phase 4: (ms=1, ks=1); ckpt kh0(t+1)
        #pragma unroll
        for (int m = 0; m < 4; m++) af[m] = *(const bf16x8*)&lds[baseA + aO + 8192 + (4 + m) * 512];
        if (pre) STAGE(nxt, 1, 1, t + 1);
        __builtin_amdgcn_s_barrier();
        asm volatile("s_waitcnt lgkmcnt(0)" ::: "memory");
        __builtin_amdgcn_sched_barrier(0);
        __builtin_amdgcn_s_setprio(1);
        #pragma unroll
        for (int m = 0; m < 4; m++)
            #pragma unroll
            for (int n = 0; n < NFRAG; n++)
                acc[4 + m][n] = __builtin_amdgcn_mfma_f32_16x16x32_bf16(af[m], bv[n], acc[4 + m][n], 0, 0, 0);
        __builtin_amdgcn_s_setprio(0);
        if (pre) { CKPT_MID(); }
        __builtin_amdgcn_sched_barrier(0);
        __builtin_amdgcn_s_barrier();
    }
    #undef CKPT_MID

    // epilogue: D layout col = lane&15, row = (lane>>4)*4 + reg [HW-verified]
    #pragma unroll
    for (int m = 0; m < 8; m++)
        #pragma unroll
        for (int n = 0; n < NFRAG; n++)
            #pragma unroll
            for (int r = 0; r < 4; r++) {
                int row = m0 + wr * 128 + m * 16 + fg * 4 + r;
                int col = n0 + wc * (BN / 4) + n * 16 + fr;
                size_t idx = (size_t)row * ldc + col;
                float v = acc[m][n][r] * scale;
                if (MODE == 0) {
                    Cf[idx] = v;
                } else if (MODE == 1) {
                    Cf[idx] = fmaxf(v + bias[col], 0.f);
                } else if (MODE == 2) {
                    Cf[idx] += fmaxf(v + bias[col], 0.f);
                } else if (MODE == 3) {
                    Cb[idx] = f2bf(v);
                } else if (MODE == 4) {
                    u16 h = f2bf(v);
                    Cb[idx]  = h;
                    Cb2[idx] = f2bf(v - bf2f(h));
                } else {                         // MODE 5: dup [kh|kh]
                    u16 h = f2bf(v);
                    Cb[idx]        = h;
                    Cb[idx + 1024] = h;
                }
            }
}

// ---------------- elementwise / converts ----------------
// x (8192x1024 f32) -> xcat2 (8192x2048 bf16): row = [hi(1024) | lo(1024)]
__global__ __launch_bounds__(256) void xsplit2_k(const float* __restrict__ s,
                                                 u16* __restrict__ d) {
    int i = blockIdx.x * 256 + threadIdx.x;    // 8192 rows x 128 chunks
    int r = i >> 7, c8 = i & 127;
    const float* src = s + (size_t)r * 1024 + c8 * 8;
    float4 a = *reinterpret_cast<const float4*>(src);
    float4 b = *reinterpret_cast<const float4*>(src + 4);
    float vals[8] = {a.x, a.y, a.z, a.w, b.x, b.y, b.z, b.w};
    union { u16 u[8]; int4 v; } th, tl;
    #pragma unroll
    for (int k = 0; k < 8; k++) {
        u16 h = f2bf(vals[k]);
        th.u[k] = h;
        tl.u[k] = f2bf(vals[k] - bf2f(h));
    }
    u16* drow = d + (size_t)r * 2048 + c8 * 8;
    *reinterpret_cast<int4*>(drow)        = th.v;
    *reinterpret_cast<int4*>(drow + 1024) = tl.v;
}

// W (1024x1024 f32) -> Wc2 (1024x2048 bf16): row = [hi | hi]
__global__ __launch_bounds__(256) void wsplit2_k(const float* __restrict__ W,
                                                 u16* __restrict__ out) {
    int i = blockIdx.x * 256 + threadIdx.x;    // 1024 rows x 128 chunks
    int r = i >> 7, c8 = i & 127;
    const float* src = W + (size_t)r * 1024 + c8 * 8;
    float4 a = *reinterpret_cast<const float4*>(src);
    float4 b = *reinterpret_cast<const float4*>(src + 4);
    union { u16 u[8]; int4 v; } th;
    th.u[0] = f2bf(a.x); th.u[1] = f2bf(a.y); th.u[2] = f2bf(a.z); th.u[3] = f2bf(a.w);
    th.u[4] = f2bf(b.x); th.u[5] = f2bf(b.y); th.u[6] = f2bf(b.z); th.u[7] = f2bf(b.w);
    u16* drow = out + (size_t)r * 2048 + c8 * 8;
    *reinterpret_cast<int4*>(drow)        = th.v;
    *reinterpret_cast<int4*>(drow + 1024) = th.v;
}

__global__ __launch_bounds__(256) void cvt_k(const float* __restrict__ s, u16* __restrict__ d) {
    int i = blockIdx.x * 256 + threadIdx.x;
    const float4* sf = reinterpret_cast<const float4*>(s);
    float4 a = sf[2 * i], b = sf[2 * i + 1];
    union { u16 u[8]; int4 v; } t;
    t.u[0] = f2bf(a.x); t.u[1] = f2bf(a.y); t.u[2] = f2bf(a.z); t.u[3] = f2bf(a.w);
    t.u[4] = f2bf(b.x); t.u[5] = f2bf(b.y); t.u[6] = f2bf(b.z); t.u[7] = f2bf(b.w);
    reinterpret_cast<int4*>(d)[i] = t.v;
}

// dbuf[i][:] = bf16(|x[i+shift][:] - x[i][:]|) for i<8188, else 0
__global__ __launch_bounds__(256) void diff_k(const float* __restrict__ x, u16* __restrict__ d, int shift) {
    int i4 = blockIdx.x * 256 + threadIdx.x;
    int row = i4 >> 8;
    const float4* xf = reinterpret_cast<const float4*>(x);
    ushort4 o;
    if (row < 8188) {
        float4 a = xf[i4 + (shift << 8)];
        float4 b = xf[i4];
        o.x = f2bf(fabsf(a.x - b.x));
        o.y = f2bf(fabsf(a.y - b.y));
        o.z = f2bf(fabsf(a.z - b.z));
        o.w = f2bf(fabsf(a.w - b.w));
    } else {
        o.x = o.y = o.z = o.w = 0;
    }
    reinterpret_cast<ushort4*>(d)[i4] = o;
}

__global__ __launch_bounds__(256) void tail_k(const float* __restrict__ x, float* __restrict__ mn) {
    int i = blockIdx.x * 256 + threadIdx.x;
    mn[8188 * 1024 + i] = x[8188 * 1024 + i];
}

// ---------------- softmax over a row of 8192 fp32 ----------------
__global__ __launch_bounds__(256) void softmax_k(const float* __restrict__ S,
                                                 float* __restrict__ aw, int row0) {
    __shared__ float red[4];
    int r = blockIdx.x, tid = threadIdx.x;
    const float4* src = reinterpret_cast<const float4*>(S + (size_t)r * 8192);
    float4 xv[8];
    float mx = -1e30f;
    #pragma unroll
    for (int j = 0; j < 8; j++) {
        xv[j] = src[tid + 256 * j];
        mx = fmaxf(mx, fmaxf(fmaxf(xv[j].x, xv[j].y), fmaxf(xv[j].z, xv[j].w)));
    }
    mx = blk_max(mx, red);
    float sum = 0.f;
    #pragma unroll
    for (int j = 0; j < 8; j++) {
        xv[j].x = __expf(xv[j].x - mx); sum += xv[j].x;
        xv[j].y = __expf(xv[j].y - mx); sum += xv[j].y;
        xv[j].z = __expf(xv[j].z - mx); sum += xv[j].z;
        xv[j].w = __expf(xv[j].w - mx); sum += xv[j].w;
    }
    sum = blk_sum(sum, red);
    float inv = 1.0f / sum;
    float4* dst = reinterpret_cast<float4*>(aw + (size_t)(row0 + r) * 8192);
    #pragma unroll
    for (int j = 0; j < 8; j++) {
        float4 o;
        o.x = xv[j].x * inv; o.y = xv[j].y * inv; o.z = xv[j].z * inv; o.w = xv[j].w * inv;
        dst[tid + 256 * j] = o;
    }
}

// ---------------- transposes (64x64 tiles) ----------------
__global__ __launch_bounds__(256) void transpose_f32_bf16(const float* __restrict__ src,
                                                          u16* __restrict__ dst) {
    __shared__ u16 t[64][72];
    int r0 = blockIdx.y * 64, c0 = blockIdx.x * 64;
    int tid = threadIdx.x;
    #pragma unroll
    for (int p = 0; p < 4; p++) {
        int q = p * 256 + tid;
        int r = q >> 4, c4 = q & 15;
        float4 v = *(reinterpret_cast<const float4*>(src + (size_t)(r0 + r) * 8192 + c0) + c4);
        t[c4 * 4 + 0][r] = f2bf(v.x);
        t[c4 * 4 + 1][r] = f2bf(v.y);
        t[c4 * 4 + 2][r] = f2bf(v.z);
        t[c4 * 4 + 3][r] = f2bf(v.w);
    }
    __syncthreads();
    #pragma unroll
    for (int p = 0; p < 2; p++) {
        int q = p * 256 + tid;
        int rr = q >> 3, cc = q & 7;
        *reinterpret_cast<int4*>(dst + (size_t)(c0 + rr) * 8192 + r0 + cc * 8) =
            *reinterpret_cast<const int4*>(&t[rr][cc * 8]);
    }
}

// bf16 transpose with leading dims; grid (srccols/64, srcrows/64)
__global__ __launch_bounds__(256) void transpose_bf16(const u16* __restrict__ src,
                                                      u16* __restrict__ dst,
                                                      int srcld, int dstld) {
    __shared__ u16 t[64][72];
    int r0 = blockIdx.y * 64, c0 = blockIdx.x * 64;
    int tid = threadIdx.x;
    #pragma unroll
    for (int p = 0; p < 2; p++) {
        int q = p * 256 + tid;
        int r = q >> 3, c8 = q & 7;
        int4 v = *(reinterpret_cast<const int4*>(src + (size_t)(r0 + r) * srcld + c0) + c8);
        const u16* u = reinterpret_cast<const u16*>(&v);
        #pragma unroll
        for (int k = 0; k < 8; k++) t[c8 * 8 + k][r] = u[k];
    }
    __syncthreads();
    #pragma unroll
    for (int p = 0; p < 2; p++) {
        int q = p * 256 + tid;
        int rr = q >> 3, cc = q & 7;
        *reinterpret_cast<int4*>(dst + (size_t)(c0 + rr) * dstld + r0 + cc * 8) =
            *reinterpret_cast<const int4*>(&t[rr][cc * 8]);
    }
}

// ---------------- LN kernels ----------------
__global__ __launch_bounds__(256) void ln_y_k(const float* __restrict__ y2, const float* __restrict__ mn,
                                              const float* __restrict__ g, const float* __restrict__ b,
                                              u16* __restrict__ zb) {
    __shared__ float red[4];
    int r = blockIdx.x, tid = threadIdx.x;
    float4 a = reinterpret_cast<const float4*>(y2 + (size_t)r * 1024)[tid];
    float4 c = reinterpret_cast<const float4*>(mn + (size_t)r * 1024)[tid];
    float4 v; v.x = a.x + c.x; v.y = a.y + c.y; v.z = a.z + c.z; v.w = a.w + c.w;
    float s  = v.x + v.y + v.z + v.w;
    float sq = v.x * v.x + v.y * v.y + v.z * v.z + v.w * v.w;
    s  = blk_sum(s, red);
    sq = blk_sum(sq, red);
    float mu = s * (1.0f / 1024.0f);
    float rs = rsqrtf(sq * (1.0f / 1024.0f) - mu * mu + LN_EPS);
    float4 gg = reinterpret_cast<const float4*>(g)[tid];
    float4 bb = reinterpret_cast<const float4*>(b)[tid];
    ushort4 o;
    o.x = f2bf((v.x - mu) * rs * gg.x + bb.x);
    o.y = f2bf((v.y - mu) * rs * gg.y + bb.y);
    o.z = f2bf((v.z - mu) * rs * gg.z + bb.z);
    o.w = f2bf((v.w - mu) * rs * gg.w + bb.w);
    reinterpret_cast<ushort4*>(zb + (size_t)r * 1024)[tid] = o;
}

__global__ __launch_bounds__(256) void ln_dot_k(const float* __restrict__ h, const float* __restrict__ g,
                                                const float* __restrict__ b, const float* __restrict__ kd,
                                                const float* __restrict__ kdb, float* __restrict__ out) {
    __shared__ float red[4];
    int r = blockIdx.x, tid = threadIdx.x;
    float4 v = reinterpret_cast<const float4*>(h + (size_t)r * 1024)[tid];
    float s  = v.x + v.y + v.z + v.w;
    float sq = v.x * v.x + v.y * v.y + v.z * v.z + v.w * v.w;
    s  = blk_sum(s, red);
    sq = blk_sum(sq, red);
    float mu = s * (1.0f / 1024.0f);
    float rs = rsqrtf(sq * (1.0f / 1024.0f) - mu * mu + LN_EPS);
    float4 gg = reinterpret_cast<const float4*>(g)[tid];
    float4 bb = reinterpret_cast<const float4*>(b)[tid];
    float4 kk = reinterpret_cast<const float4*>(kd)[tid];
    float part = ((v.x - mu) * rs * gg.x + bb.x) * kk.x
               + ((v.y - mu) * rs * gg.y + bb.y) * kk.y
               + ((v.z - mu) * rs * gg.z + bb.z) * kk.z
               + ((v.w - mu) * rs * gg.w + bb.w) * kk.w;
    part = blk_sum(part, red);
    if (tid == 0) out[r] = 1.0f / (1.0f + __expf(-(part + kdb[0])));
}

// ---------------- launch ----------------
extern "C" void kernel_launch(void* const* d_in, const int* in_sizes, int n_in,
                              void* d_out, int out_size, void* d_ws, size_t ws_size,
                              hipStream_t stream) {
    (void)in_sizes; (void)n_in; (void)out_size; (void)ws_size;
    const float* x    = (const float*)d_in[0];
    const float* Wq   = (const float*)d_in[2];
    const float* Wk   = (const float*)d_in[3];
    const float* Wv   = (const float*)d_in[4];
    const float* Wo   = (const float*)d_in[5];
    const float* fc1w = (const float*)d_in[6];
    const float* fc1b = (const float*)d_in[7];
    const float* kaw  = (const float*)d_in[8];
    const float* kab  = (const float*)d_in[9];
    const float* kdw  = (const float*)d_in[10];
    const float* kdb  = (const float*)d_in[11];
    const float* lyg  = (const float*)d_in[12];
    const float* lyb  = (const float*)d_in[13];
    const float* lkg  = (const float*)d_in[14];
    const float* lkb  = (const float*)d_in[15];

    float* out0 = (float*)d_out;
    float* aw   = out0 + 8192;

    char* base = (char*)d_ws;
    size_t off = 0;
    auto alloc = [&](size_t bytes) -> char* {
        char* p = base + off;
        off += (bytes + 255) & ~(size_t)255;
        return p;
    };
    const size_t NM = 8192ULL * 1024ULL;
    u16*   ST   = (u16*)alloc(8192ULL * 8192ULL * 2);   // 128MB; first 64MB doubles as Sf
    float* Sf   = (float*)ST;                           // 2048x8192 fp32 chunk
    u16*   xcat = (u16*)alloc(8192ULL * 2048ULL * 2);   // [xh|xl] rows, 32MB
    u16*   Qi   = (u16*)alloc(8192ULL * 2048ULL * 2);   // [qh|ql] rows, 32MB
    u16*   Ki   = (u16*)alloc(8192ULL * 2048ULL * 2);   // [kh|kh] rows, 32MB
    u16*   Vb   = (u16*)alloc(NM * 2);
    u16*   Vt   = (u16*)alloc(NM * 2);
    u16*   dbuf = (u16*)alloc(NM * 2);                  // later reused as zb
    u16*   yb   = (u16*)alloc(NM * 2);
    float* mn   = (float*)alloc(NM * 4);
    float* y2   = (float*)alloc(NM * 4);
    float* hbuf = (float*)alloc(NM * 4);
    u16*   Wqc  = (u16*)alloc(1024ULL * 2048ULL * 2);   // [Wqh|Wqh]
    u16*   Wkc  = (u16*)alloc(1024ULL * 2048ULL * 2);   // [Wkh|Wkh]
    u16*   Wvb  = (u16*)alloc(1048576ULL * 2);
    u16*   fwb  = (u16*)alloc(1048576ULL * 2);
    u16*   Wob  = (u16*)alloc(1048576ULL * 2);
    u16*   kwb  = (u16*)alloc(1048576ULL * 2);
    u16*   zb   = dbuf;

    // 1) converts / splits
    xsplit2_k<<<4096, 256, 0, stream>>>(x, xcat);
    wsplit2_k<<<512, 256, 0, stream>>>(Wq, Wqc);
    wsplit2_k<<<512, 256, 0, stream>>>(Wk, Wkc);
    cvt_k<<<512, 256, 0, stream>>>(Wv, Wvb);
    cvt_k<<<512, 256, 0, stream>>>(fc1w, fwb);
    cvt_k<<<512, 256, 0, stream>>>(Wo, Wob);
    cvt_k<<<512, 256, 0, stream>>>(kaw, kwb);

    // 2) mn branch: 3x (diff -> BN=128 gemm8), then tail rows
    diff_k<<<8192, 256, 0, stream>>>(x, dbuf, 1);
    gemm8_k<128, 1><<<dim3(8, 32), 512, 0, stream>>>(
        dbuf, 1024, fwb, 1024, mn, nullptr, nullptr, fc1b, 1024, 1024, 1.0f);
    diff_k<<<8192, 256, 0, stream>>>(x, dbuf, 2);
    gemm8_k<128, 2><<<dim3(8, 32), 512, 0, stream>>>(
        dbuf, 1024, fwb, 1024, mn, nullptr, nullptr, fc1b, 1024, 1024, 1.0f);
    diff_k<<<8192, 256, 0, stream>>>(x, dbuf, 4);
    gemm8_k<128, 2><<<dim3(8, 32), 512, 0, stream>>>(
        dbuf, 1024, fwb, 1024, mn, nullptr, nullptr, fc1b, 1024, 1024, 1.0f);
    tail_k<<<16, 256, 0, stream>>>(x, mn);

    // 3) projections (no concat copies):
    //    Q: [xh|xl]@[Wqh|Wqh] K=2048 -> Qi=[qh|ql] (interleaved via Cb/Cb2)
    //    K: same shape -> Ki=[kh|kh] (MODE 5 dup)
    //    V: K=1024 over xh half of xcat
    gemm8_k<128, 4><<<dim3(8, 32), 512, 0, stream>>>(
        xcat, 2048, Wqc, 2048, nullptr, Qi, Qi + 1024, nullptr, 2048, 2048, 0.06f);
    gemm8_k<128, 5><<<dim3(8, 32), 512, 0, stream>>>(
        xcat, 2048, Wkc, 2048, nullptr, Ki, nullptr, nullptr, 2048, 2048, 1.0f);
    gemm8_k<128, 3><<<dim3(8, 32), 512, 0, stream>>>(
        xcat, 2048, Wvb, 1024, nullptr, Vb, nullptr, nullptr, 1024, 1024, 1.0f);
    transpose_bf16<<<dim3(16, 128), 256, 0, stream>>>(Vb, Vt, 1024, 8192);

    // 4) logits = (qh+ql)·kh via K=2048 GEMM on interleaved layouts; softmax
    for (int c = 0; c < 4; ++c) {
        gemm8_k<256, 0><<<dim3(32, 8), 512, 0, stream>>>(
            Qi + (size_t)c * 2048 * 2048, 2048, Ki, 2048,
            Sf, nullptr, nullptr, nullptr, 8192, 2048, 1.0f);
        softmax_k<<<2048, 256, 0, stream>>>(Sf, aw, c * 2048);
    }

    // 5) ST = aw^T (bf16); yb = bf16(ST @ Vt^T)  (== aw^T @ V), BN=128
    transpose_f32_bf16<<<dim3(128, 128), 256, 0, stream>>>(aw, ST);
    gemm8_k<128, 3><<<dim3(8, 32), 512, 0, stream>>>(
        ST, 8192, Vt, 8192, nullptr, yb, nullptr, nullptr, 1024, 8192, 1.0f);

    // 6) head: y2 = yb@Wo^T ; zb = LN(y2+mn) ; h = relu(zb@ka^T+b) ; out
    gemm8_k<128, 0><<<dim3(8, 32), 512, 0, stream>>>(
        yb, 1024, Wob, 1024, y2, nullptr, nullptr, nullptr, 1024, 1024, 1.0f);
    ln_y_k<<<8192, 256, 0, stream>>>(y2, mn, lyg, lyb, zb);
    gemm8_k<128, 1><<<dim3(8, 32), 512, 0, stream>>>(
        zb, 1024, kwb, 1024, hbuf, nullptr, nullptr, kab, 1024, 1024, 1.0f);
    ln_dot_k<<<8192, 256, 0, stream>>>(hbuf, lkg, lkb, kdw, kdb, out0);
}

// Round 7
// 811.609 us; speedup vs baseline: 1.9732x; 1.1947x over previous
//
#include <hip/hip_runtime.h>
#include <cstdint>
#include <cstddef>

typedef unsigned short u16;
typedef short bf16x8 __attribute__((ext_vector_type(8)));
typedef float f32x4 __attribute__((ext_vector_type(4)));

#define LN_EPS 1e-6f

// async global->LDS, 16B per lane; LDS dest is wave-uniform base + lane*16
#define GLD16(gsrc, ldst) \
    __builtin_amdgcn_global_load_lds( \
        (const __attribute__((address_space(1))) void*)(gsrc), \
        (__attribute__((address_space(3))) void*)(ldst), 16, 0, 0)

__device__ inline u16 f2bf(float f) {
    uint32_t x = __float_as_uint(f);
    uint32_t r = (x + 0x7fffu + ((x >> 16) & 1u)) >> 16;   // RNE
    return (u16)r;
}
__device__ inline float bf2f(u16 u) { return __uint_as_float(((uint32_t)u) << 16); }

// ---------------- block reductions (256 threads = 4 waves) ----------------
__device__ inline float blk_sum(float v, float* s) {
    #pragma unroll
    for (int o = 32; o > 0; o >>= 1) v += __shfl_xor(v, o);
    __syncthreads();
    if ((threadIdx.x & 63) == 0) s[threadIdx.x >> 6] = v;
    __syncthreads();
    return s[0] + s[1] + s[2] + s[3];
}
__device__ inline float blk_max(float v, float* s) {
    #pragma unroll
    for (int o = 32; o > 0; o >>= 1) v = fmaxf(v, __shfl_xor(v, o));
    __syncthreads();
    if ((threadIdx.x & 63) == 0) s[threadIdx.x >> 6] = v;
    __syncthreads();
    return fmaxf(fmaxf(s[0], s[1]), fmaxf(s[2], s[3]));
}

// =====================================================================
// 8-phase 256xBN GEMM (m201-template port; R3/R5/R6-validated structure).
// C[m][n] = sum_k A[m][k]*B[n][k], row-major k-contiguous.
// BN in {256,128}: 8 waves as 2(M)x4(N), per-wave 128 x BN/4.
// BK=64 staged as 2 k-halves; double-buffered LDS; counted vmcnt ckpts
// (4 for BN=256, 3 for BN=128) at phases 2/4 — never drain-0 mid-loop.
// LDS 16B-slot swizzle on global SOURCE col + ds_read addr (rule #21).
// Grid (N/BN, M/256); requires gridDim.x*gridDim.y % 8 == 0; 128/96 KiB
// LDS -> 1 block/CU, so use exactly 256 blocks for full-chip dispatches.
// MODE: 0 f32*scale | 1 f32 relu(acc+bias) | 2 f32 += relu(acc+bias)
//       | 3 bf16*scale
// =====================================================================
template<int BN, int MODE>
__global__ __launch_bounds__(512, 2) void gemm8_k(
    const u16* __restrict__ A, int lda, const u16* __restrict__ B, int ldb,
    float* __restrict__ Cf, u16* __restrict__ Cb,
    const float* __restrict__ bias, int ldc, int K, float scale)
{
    constexpr int NFRAG = BN / 64;          // n-fragments per wave
    constexpr int BKH   = BN * 32;          // B per-kh elems
    constexpr int BUFE  = 16384 + BN * 64;  // elems per buffer (A 2kh + B 2kh)
    __shared__ u16 lds[2 * BUFE];

    const int tid  = threadIdx.x;
    const int lane = tid & 63, wid = tid >> 6;
    const int wr = wid >> 2, wc = wid & 3;
    const int fr = lane & 15, fg = lane >> 4;

    const int gx  = gridDim.x, nwg = gx * gridDim.y;
    const int bid = blockIdx.y * gx + blockIdx.x;
    const int wg  = (bid & 7) * (nwg >> 3) + (bid >> 3);   // XCD-contiguous
    const int n0  = (wg % gx) * BN, m0 = (wg / gx) * 256;

    // staging geometry: thread covers row sr (and sr+128 for 256-row tiles)
    const int sr = tid >> 2;
    const int kb = ((tid & 3) ^ ((sr >> 1) & 3)) * 8;   // pre-swizzled col

    f32x4 acc[8][NFRAG];
    {
        f32x4 z = {0.f, 0.f, 0.f, 0.f};
        #pragma unroll
        for (int m = 0; m < 8; m++)
            #pragma unroll
            for (int n = 0; n < NFRAG; n++) acc[m][n] = z;
    }

    const int NT = K >> 6;

    auto STAGE = [&](int buf, int isB, int kh, int kt) {
        const u16* s0 = isB ? B : A;
        const int  ld = isB ? ldb : lda;
        const int  rb = isB ? n0 : m0;
        const int  k0 = kt * 64 + kh * 32 + kb;
        u16* dst = &lds[buf * BUFE + (isB ? 16384 : 0) + kh * (isB ? BKH : 8192) + tid * 8];
        GLD16(s0 + (size_t)(rb + sr) * ld + k0, dst);
        if (!isB || BN == 256)
            GLD16(s0 + (size_t)(rb + 128 + sr) * ld + k0, dst + 4096);
    };

    #define CKPT_MID() do { if constexpr (BN == 256) asm volatile("s_waitcnt vmcnt(4)" ::: "memory"); \
                            else                     asm volatile("s_waitcnt vmcnt(3)" ::: "memory"); } while (0)

    // per-lane read bases (u16 units)
    const int swz   = (fg ^ ((fr >> 1) & 3)) * 8;
    const int baseA = (wr * 128 + fr) * 32 + swz;
    const int baseB = 16384 + (wc * (BN / 4) + fr) * 32 + swz;

    // prologue: A-kh0, B-kh0, A-kh1, B-kh1 of tile 0
    STAGE(0, 0, 0, 0); STAGE(0, 1, 0, 0); STAGE(0, 0, 1, 0); STAGE(0, 1, 1, 0);
    CKPT_MID();                                            // kh0 group landed
    __builtin_amdgcn_s_barrier();

    bf16x8 af[4], bv[NFRAG];

    for (int t = 0; t < NT; ++t) {
        const int  aO  = (t & 1) * BUFE;
        const int  nxt = (t & 1) ^ 1;
        const bool pre = (t + 1 < NT);

        // ---- phase 1: (ms=0, ks=0)
        #pragma unroll
        for (int m = 0; m < 4; m++) af[m] = *(const bf16x8*)&lds[baseA + aO + m * 512];
        #pragma unroll
        for (int n = 0; n < NFRAG; n++) bv[n] = *(const bf16x8*)&lds[baseB + aO + n * 512];
        if (pre) STAGE(nxt, 0, 0, t + 1);
        __builtin_amdgcn_s_barrier();
        asm volatile("s_waitcnt lgkmcnt(0)" ::: "memory");
        __builtin_amdgcn_sched_barrier(0);
        __builtin_amdgcn_s_setprio(1);
        #pragma unroll
        for (int m = 0; m < 4; m++)
            #pragma unroll
            for (int n = 0; n < NFRAG; n++)
                acc[m][n] = __builtin_amdgcn_mfma_f32_16x16x32_bf16(af[m], bv[n], acc[m][n], 0, 0, 0);
        __builtin_amdgcn_s_setprio(0);
        __builtin_amdgcn_s_barrier();

        // ---- phase 2: (ms=1, ks=0); ckpt kh1(t)
        #pragma unroll
        for (int m = 0; m < 4; m++) af[m] = *(const bf16x8*)&lds[baseA + aO + (4 + m) * 512];
        if (pre) STAGE(nxt, 1, 0, t + 1);
        __builtin_amdgcn_s_barrier();
        asm volatile("s_waitcnt lgkmcnt(0)" ::: "memory");
        __builtin_amdgcn_sched_barrier(0);
        __builtin_amdgcn_s_setprio(1);
        #pragma unroll
        for (int m = 0; m < 4; m++)
            #pragma unroll
            for (int n = 0; n < NFRAG; n++)
                acc[4 + m][n] = __builtin_amdgcn_mfma_f32_16x16x32_bf16(af[m], bv[n], acc[4 + m][n], 0, 0, 0);
        __builtin_amdgcn_s_setprio(0);
        if (pre) { CKPT_MID(); }
        else     { asm volatile("s_waitcnt vmcnt(0)" ::: "memory"); }
        __builtin_amdgcn_sched_barrier(0);
        __builtin_amdgcn_s_barrier();

        // ---- phase 3: (ms=0, ks=1)
        #pragma unroll
        for (int m = 0; m < 4; m++) af[m] = *(const bf16x8*)&lds[baseA + aO + 8192 + m * 512];
        #pragma unroll
        for (int n = 0; n < NFRAG; n++) bv[n] = *(const bf16x8*)&lds[baseB + aO + BKH + n * 512];
        if (pre) STAGE(nxt, 0, 1, t + 1);
        __builtin_amdgcn_s_barrier();
        asm volatile("s_waitcnt lgkmcnt(0)" ::: "memory");
        __builtin_amdgcn_sched_barrier(0);
        __builtin_amdgcn_s_setprio(1);
        #pragma unroll
        for (int m = 0; m < 4; m++)
            #pragma unroll
            for (int n = 0; n < NFRAG; n++)
                acc[m][n] = __builtin_amdgcn_mfma_f32_16x16x32_bf16(af[m], bv[n], acc[m][n], 0, 0, 0);
        __builtin_amdgcn_s_setprio(0);
        __builtin_amdgcn_s_barrier();

        // ---- phase 4: (ms=1, ks=1); ckpt kh0(t+1)
        #pragma unroll
        for (int m = 0; m < 4; m++) af[m] = *(const bf16x8*)&lds[baseA + aO + 8192 + (4 + m) * 512];
        if (pre) STAGE(nxt, 1, 1, t + 1);
        __builtin_amdgcn_s_barrier();
        asm volatile("s_waitcnt lgkmcnt(0)" ::: "memory");
        __builtin_amdgcn_sched_barrier(0);
        __builtin_amdgcn_s_setprio(1);
        #pragma unroll
        for (int m = 0; m < 4; m++)
            #pragma unroll
            for (int n = 0; n < NFRAG; n++)
                acc[4 + m][n] = __builtin_amdgcn_mfma_f32_16x16x32_bf16(af[m], bv[n], acc[4 + m][n], 0, 0, 0);
        __builtin_amdgcn_s_setprio(0);
        if (pre) { CKPT_MID(); }
        __builtin_amdgcn_sched_barrier(0);
        __builtin_amdgcn_s_barrier();
    }
    #undef CKPT_MID

    // epilogue: D layout col = lane&15, row = (lane>>4)*4 + reg [HW-verified]
    #pragma unroll
    for (int m = 0; m < 8; m++)
        #pragma unroll
        for (int n = 0; n < NFRAG; n++)
            #pragma unroll
            for (int r = 0; r < 4; r++) {
                int row = m0 + wr * 128 + m * 16 + fg * 4 + r;
                int col = n0 + wc * (BN / 4) + n * 16 + fr;
                size_t idx = (size_t)row * ldc + col;
                float v = acc[m][n][r] * scale;
                if (MODE == 0) {
                    Cf[idx] = v;
                } else if (MODE == 1) {
                    Cf[idx] = fmaxf(v + bias[col], 0.f);
                } else if (MODE == 2) {
                    Cf[idx] += fmaxf(v + bias[col], 0.f);
                } else {
                    Cb[idx] = f2bf(v);
                }
            }
}

// ---------------- elementwise / converts ----------------
__global__ __launch_bounds__(256) void cvt_k(const float* __restrict__ s, u16* __restrict__ d) {
    int i = blockIdx.x * 256 + threadIdx.x;
    const float4* sf = reinterpret_cast<const float4*>(s);
    float4 a = sf[2 * i], b = sf[2 * i + 1];
    union { u16 u[8]; int4 v; } t;
    t.u[0] = f2bf(a.x); t.u[1] = f2bf(a.y); t.u[2] = f2bf(a.z); t.u[3] = f2bf(a.w);
    t.u[4] = f2bf(b.x); t.u[5] = f2bf(b.y); t.u[6] = f2bf(b.z); t.u[7] = f2bf(b.w);
    reinterpret_cast<int4*>(d)[i] = t.v;
}

// dbuf[i][:] = bf16(|x[i+shift][:] - x[i][:]|) for i<8188, else 0
__global__ __launch_bounds__(256) void diff_k(const float* __restrict__ x, u16* __restrict__ d, int shift) {
    int i4 = blockIdx.x * 256 + threadIdx.x;
    int row = i4 >> 8;
    const float4* xf = reinterpret_cast<const float4*>(x);
    ushort4 o;
    if (row < 8188) {
        float4 a = xf[i4 + (shift << 8)];
        float4 b = xf[i4];
        o.x = f2bf(fabsf(a.x - b.x));
        o.y = f2bf(fabsf(a.y - b.y));
        o.z = f2bf(fabsf(a.z - b.z));
        o.w = f2bf(fabsf(a.w - b.w));
    } else {
        o.x = o.y = o.z = o.w = 0;
    }
    reinterpret_cast<ushort4*>(d)[i4] = o;
}

__global__ __launch_bounds__(256) void tail_k(const float* __restrict__ x, float* __restrict__ mn) {
    int i = blockIdx.x * 256 + threadIdx.x;
    mn[8188 * 1024 + i] = x[8188 * 1024 + i];
}

// ---------------- softmax over a row of 8192 fp32 ----------------
__global__ __launch_bounds__(256) void softmax_k(const float* __restrict__ S,
                                                 float* __restrict__ aw, int row0) {
    __shared__ float red[4];
    int r = blockIdx.x, tid = threadIdx.x;
    const float4* src = reinterpret_cast<const float4*>(S + (size_t)r * 8192);
    float4 xv[8];
    float mx = -1e30f;
    #pragma unroll
    for (int j = 0; j < 8; j++) {
        xv[j] = src[tid + 256 * j];
        mx = fmaxf(mx, fmaxf(fmaxf(xv[j].x, xv[j].y), fmaxf(xv[j].z, xv[j].w)));
    }
    mx = blk_max(mx, red);
    float sum = 0.f;
    #pragma unroll
    for (int j = 0; j < 8; j++) {
        xv[j].x = __expf(xv[j].x - mx); sum += xv[j].x;
        xv[j].y = __expf(xv[j].y - mx); sum += xv[j].y;
        xv[j].z = __expf(xv[j].z - mx); sum += xv[j].z;
        xv[j].w = __expf(xv[j].w - mx); sum += xv[j].w;
    }
    sum = blk_sum(sum, red);
    float inv = 1.0f / sum;
    float4* dst = reinterpret_cast<float4*>(aw + (size_t)(row0 + r) * 8192);
    #pragma unroll
    for (int j = 0; j < 8; j++) {
        float4 o;
        o.x = xv[j].x * inv; o.y = xv[j].y * inv; o.z = xv[j].z * inv; o.w = xv[j].w * inv;
        dst[tid + 256 * j] = o;
    }
}

// ---------------- transposes (64x64 tiles) ----------------
__global__ __launch_bounds__(256) void transpose_f32_bf16(const float* __restrict__ src,
                                                          u16* __restrict__ dst) {
    __shared__ u16 t[64][72];
    int r0 = blockIdx.y * 64, c0 = blockIdx.x * 64;
    int tid = threadIdx.x;
    #pragma unroll
    for (int p = 0; p < 4; p++) {
        int q = p * 256 + tid;
        int r = q >> 4, c4 = q & 15;
        float4 v = *(reinterpret_cast<const float4*>(src + (size_t)(r0 + r) * 8192 + c0) + c4);
        t[c4 * 4 + 0][r] = f2bf(v.x);
        t[c4 * 4 + 1][r] = f2bf(v.y);
        t[c4 * 4 + 2][r] = f2bf(v.z);
        t[c4 * 4 + 3][r] = f2bf(v.w);
    }
    __syncthreads();
    #pragma unroll
    for (int p = 0; p < 2; p++) {
        int q = p * 256 + tid;
        int rr = q >> 3, cc = q & 7;
        *reinterpret_cast<int4*>(dst + (size_t)(c0 + rr) * 8192 + r0 + cc * 8) =
            *reinterpret_cast<const int4*>(&t[rr][cc * 8]);
    }
}

// bf16 transpose with leading dims; grid (srccols/64, srcrows/64)
__global__ __launch_bounds__(256) void transpose_bf16(const u16* __restrict__ src,
                                                      u16* __restrict__ dst,
                                                      int srcld, int dstld) {
    __shared__ u16 t[64][72];
    int r0 = blockIdx.y * 64, c0 = blockIdx.x * 64;
    int tid = threadIdx.x;
    #pragma unroll
    for (int p = 0; p < 2; p++) {
        int q = p * 256 + tid;
        int r = q >> 3, c8 = q & 7;
        int4 v = *(reinterpret_cast<const int4*>(src + (size_t)(r0 + r) * srcld + c0) + c8);
        const u16* u = reinterpret_cast<const u16*>(&v);
        #pragma unroll
        for (int k = 0; k < 8; k++) t[c8 * 8 + k][r] = u[k];
    }
    __syncthreads();
    #pragma unroll
    for (int p = 0; p < 2; p++) {
        int q = p * 256 + tid;
        int rr = q >> 3, cc = q & 7;
        *reinterpret_cast<int4*>(dst + (size_t)(c0 + rr) * dstld + r0 + cc * 8) =
            *reinterpret_cast<const int4*>(&t[rr][cc * 8]);
    }
}

// ---------------- LN kernels ----------------
__global__ __launch_bounds__(256) void ln_y_k(const float* __restrict__ y2, const float* __restrict__ mn,
                                              const float* __restrict__ g, const float* __restrict__ b,
                                              u16* __restrict__ zb) {
    __shared__ float red[4];
    int r = blockIdx.x, tid = threadIdx.x;
    float4 a = reinterpret_cast<const float4*>(y2 + (size_t)r * 1024)[tid];
    float4 c = reinterpret_cast<const float4*>(mn + (size_t)r * 1024)[tid];
    float4 v; v.x = a.x + c.x; v.y = a.y + c.y; v.z = a.z + c.z; v.w = a.w + c.w;
    float s  = v.x + v.y + v.z + v.w;
    float sq = v.x * v.x + v.y * v.y + v.z * v.z + v.w * v.w;
    s  = blk_sum(s, red);
    sq = blk_sum(sq, red);
    float mu = s * (1.0f / 1024.0f);
    float rs = rsqrtf(sq * (1.0f / 1024.0f) - mu * mu + LN_EPS);
    float4 gg = reinterpret_cast<const float4*>(g)[tid];
    float4 bb = reinterpret_cast<const float4*>(b)[tid];
    ushort4 o;
    o.x = f2bf((v.x - mu) * rs * gg.x + bb.x);
    o.y = f2bf((v.y - mu) * rs * gg.y + bb.y);
    o.z = f2bf((v.z - mu) * rs * gg.z + bb.z);
    o.w = f2bf((v.w - mu) * rs * gg.w + bb.w);
    reinterpret_cast<ushort4*>(zb + (size_t)r * 1024)[tid] = o;
}

__global__ __launch_bounds__(256) void ln_dot_k(const float* __restrict__ h, const float* __restrict__ g,
                                                const float* __restrict__ b, const float* __restrict__ kd,
                                                const float* __restrict__ kdb, float* __restrict__ out) {
    __shared__ float red[4];
    int r = blockIdx.x, tid = threadIdx.x;
    float4 v = reinterpret_cast<const float4*>(h + (size_t)r * 1024)[tid];
    float s  = v.x + v.y + v.z + v.w;
    float sq = v.x * v.x + v.y * v.y + v.z * v.z + v.w * v.w;
    s  = blk_sum(s, red);
    sq = blk_sum(sq, red);
    float mu = s * (1.0f / 1024.0f);
    float rs = rsqrtf(sq * (1.0f / 1024.0f) - mu * mu + LN_EPS);
    float4 gg = reinterpret_cast<const float4*>(g)[tid];
    float4 bb = reinterpret_cast<const float4*>(b)[tid];
    float4 kk = reinterpret_cast<const float4*>(kd)[tid];
    float part = ((v.x - mu) * rs * gg.x + bb.x) * kk.x
               + ((v.y - mu) * rs * gg.y + bb.y) * kk.y
               + ((v.z - mu) * rs * gg.z + bb.z) * kk.z
               + ((v.w - mu) * rs * gg.w + bb.w) * kk.w;
    part = blk_sum(part, red);
    if (tid == 0) out[r] = 1.0f / (1.0f + __expf(-(part + kdb[0])));
}

// ---------------- launch ----------------
extern "C" void kernel_launch(void* const* d_in, const int* in_sizes, int n_in,
                              void* d_out, int out_size, void* d_ws, size_t ws_size,
                              hipStream_t stream) {
    (void)in_sizes; (void)n_in; (void)out_size; (void)ws_size;
    const float* x    = (const float*)d_in[0];
    const float* Wq   = (const float*)d_in[2];
    const float* Wk   = (const float*)d_in[3];
    const float* Wv   = (const float*)d_in[4];
    const float* Wo   = (const float*)d_in[5];
    const float* fc1w = (const float*)d_in[6];
    const float* fc1b = (const float*)d_in[7];
    const float* kaw  = (const float*)d_in[8];
    const float* kab  = (const float*)d_in[9];
    const float* kdw  = (const float*)d_in[10];
    const float* kdb  = (const float*)d_in[11];
    const float* lyg  = (const float*)d_in[12];
    const float* lyb  = (const float*)d_in[13];
    const float* lkg  = (const float*)d_in[14];
    const float* lkb  = (const float*)d_in[15];

    float* out0 = (float*)d_out;
    float* aw   = out0 + 8192;

    char* base = (char*)d_ws;
    size_t off = 0;
    auto alloc = [&](size_t bytes) -> char* {
        char* p = base + off;
        off += (bytes + 255) & ~(size_t)255;
        return p;
    };
    const size_t NM = 8192ULL * 1024ULL;
    u16*   ST   = (u16*)alloc(8192ULL * 8192ULL * 2);   // 128MB; first 64MB doubles as Sf
    float* Sf   = (float*)ST;                           // 2048x8192 fp32 chunk
    u16*   xb   = (u16*)alloc(NM * 2);
    u16*   Qb   = (u16*)alloc(NM * 2);
    u16*   Kb   = (u16*)alloc(NM * 2);
    u16*   Vb   = (u16*)alloc(NM * 2);
    u16*   Vt   = (u16*)alloc(NM * 2);
    u16*   dbuf = (u16*)alloc(NM * 2);                  // later reused as zb
    u16*   yb   = (u16*)alloc(NM * 2);
    float* mn   = (float*)alloc(NM * 4);
    float* y2   = (float*)alloc(NM * 4);
    float* hbuf = (float*)alloc(NM * 4);
    u16*   Wqb  = (u16*)alloc(1048576ULL * 2);
    u16*   Wkb  = (u16*)alloc(1048576ULL * 2);
    u16*   Wvb  = (u16*)alloc(1048576ULL * 2);
    u16*   fwb  = (u16*)alloc(1048576ULL * 2);
    u16*   Wob  = (u16*)alloc(1048576ULL * 2);
    u16*   kwb  = (u16*)alloc(1048576ULL * 2);
    u16*   zb   = dbuf;

    // 1) converts (all plain bf16 — error analysis: logits ΔS σ≈2.2e-3,
    //    aw check needs max|ΔS| < 0.02 → ~2x margin)
    cvt_k<<<4096, 256, 0, stream>>>(x, xb);
    cvt_k<<<512, 256, 0, stream>>>(Wq, Wqb);
    cvt_k<<<512, 256, 0, stream>>>(Wk, Wkb);
    cvt_k<<<512, 256, 0, stream>>>(Wv, Wvb);
    cvt_k<<<512, 256, 0, stream>>>(fc1w, fwb);
    cvt_k<<<512, 256, 0, stream>>>(Wo, Wob);
    cvt_k<<<512, 256, 0, stream>>>(kaw, kwb);

    // 2) mn branch: 3x (diff -> BN=128 gemm8), then tail rows
    diff_k<<<8192, 256, 0, stream>>>(x, dbuf, 1);
    gemm8_k<128, 1><<<dim3(8, 32), 512, 0, stream>>>(
        dbuf, 1024, fwb, 1024, mn, nullptr, fc1b, 1024, 1024, 1.0f);
    diff_k<<<8192, 256, 0, stream>>>(x, dbuf, 2);
    gemm8_k<128, 2><<<dim3(8, 32), 512, 0, stream>>>(
        dbuf, 1024, fwb, 1024, mn, nullptr, fc1b, 1024, 1024, 1.0f);
    diff_k<<<8192, 256, 0, stream>>>(x, dbuf, 4);
    gemm8_k<128, 2><<<dim3(8, 32), 512, 0, stream>>>(
        dbuf, 1024, fwb, 1024, mn, nullptr, fc1b, 1024, 1024, 1.0f);
    tail_k<<<16, 256, 0, stream>>>(x, mn);

    // 3) projections: Q (x0.06), K, V — plain bf16 K=1024 GEMMs
    gemm8_k<128, 3><<<dim3(8, 32), 512, 0, stream>>>(
        xb, 1024, Wqb, 1024, nullptr, Qb, nullptr, 1024, 1024, 0.06f);
    gemm8_k<128, 3><<<dim3(8, 32), 512, 0, stream>>>(
        xb, 1024, Wkb, 1024, nullptr, Kb, nullptr, 1024, 1024, 1.0f);
    gemm8_k<128, 3><<<dim3(8, 32), 512, 0, stream>>>(
        xb, 1024, Wvb, 1024, nullptr, Vb, nullptr, 1024, 1024, 1.0f);
    transpose_bf16<<<dim3(16, 128), 256, 0, stream>>>(Vb, Vt, 1024, 8192);

    // 4) logits = Q·K^T via K=1024 BN=256 GEMM; softmax into aw (d_out)
    for (int c = 0; c < 4; ++c) {
        gemm8_k<256, 0><<<dim3(32, 8), 512, 0, stream>>>(
            Qb + (size_t)c * 2048 * 1024, 1024, Kb, 1024,
            Sf, nullptr, nullptr, 8192, 1024, 1.0f);
        softmax_k<<<2048, 256, 0, stream>>>(Sf, aw, c * 2048);
    }

    // 5) ST = aw^T (bf16); yb = bf16(ST @ Vt^T)  (== aw^T @ V), BN=128
    transpose_f32_bf16<<<dim3(128, 128), 256, 0, stream>>>(aw, ST);
    gemm8_k<128, 3><<<dim3(8, 32), 512, 0, stream>>>(
        ST, 8192, Vt, 8192, nullptr, yb, nullptr, 1024, 8192, 1.0f);

    // 6) head: y2 = yb@Wo^T ; zb = LN(y2+mn) ; h = relu(zb@ka^T+b) ; out
    gemm8_k<128, 0><<<dim3(8, 32), 512, 0, stream>>>(
        yb, 1024, Wob, 1024, y2, nullptr, nullptr, 1024, 1024, 1.0f);
    ln_y_k<<<8192, 256, 0, stream>>>(y2, mn, lyg, lyb, zb);
    gemm8_k<128, 1><<<dim3(8, 32), 512, 0, stream>>>(
        zb, 1024, kwb, 1024, hbuf, nullptr, kab, 1024, 1024, 1.0f);
    ln_dot_k<<<8192, 256, 0, stream>>>(hbuf, lkg, lkb, kdw, kdb, out0);
}

// Round 8
// 784.454 us; speedup vs baseline: 2.0415x; 1.0346x over previous
//
#include <hip/hip_runtime.h>
#include <cstdint>
#include <cstddef>

typedef unsigned short u16;
typedef short bf16x8 __attribute__((ext_vector_type(8)));
typedef float f32x4 __attribute__((ext_vector_type(4)));

#define LN_EPS 1e-6f

// async global->LDS, 16B per lane; LDS dest is wave-uniform base + lane*16
#define GLD16(gsrc, ldst) \
    __builtin_amdgcn_global_load_lds( \
        (const __attribute__((address_space(1))) void*)(gsrc), \
        (__attribute__((address_space(3))) void*)(ldst), 16, 0, 0)

__device__ inline u16 f2bf(float f) {
    uint32_t x = __float_as_uint(f);
    uint32_t r = (x + 0x7fffu + ((x >> 16) & 1u)) >> 16;   // RNE
    return (u16)r;
}
__device__ inline float bf2f(u16 u) { return __uint_as_float(((uint32_t)u) << 16); }

// ---------------- block reductions (256 threads = 4 waves) ----------------
__device__ inline float blk_sum(float v, float* s) {
    #pragma unroll
    for (int o = 32; o > 0; o >>= 1) v += __shfl_xor(v, o);
    __syncthreads();
    if ((threadIdx.x & 63) == 0) s[threadIdx.x >> 6] = v;
    __syncthreads();
    return s[0] + s[1] + s[2] + s[3];
}
__device__ inline float blk_max(float v, float* s) {
    #pragma unroll
    for (int o = 32; o > 0; o >>= 1) v = fmaxf(v, __shfl_xor(v, o));
    __syncthreads();
    if ((threadIdx.x & 63) == 0) s[threadIdx.x >> 6] = v;
    __syncthreads();
    return fmaxf(fmaxf(s[0], s[1]), fmaxf(s[2], s[3]));
}

// =====================================================================
// 8-phase 256xBN GEMM (m201-template port; validated R3/R5/R6/R7).
// C[m][n] = sum_k A[m][k]*B[n][k], row-major k-contiguous.
// BN in {256,128}: 8 waves as 2(M)x4(N), per-wave 128 x BN/4.
// BK=64 staged as 2 k-halves; double-buffered LDS; counted vmcnt ckpts
// (4 for BN=256, 3 for BN=128) at phases 2/4 — never drain-0 mid-loop.
// LDS 16B-slot swizzle on global SOURCE col + ds_read addr (rule #21).
// Grid (N/BN, M/256, Z); Z split-K: A,B advance z*K elems, C advances
// z*zCstride floats. gridDim.x*gridDim.y % 8 == 0; use 256 blocks/round.
// MODE: 0 f32*scale | 1 f32 relu(acc+bias) | 2 f32 += relu(acc+bias)
//       | 3 bf16*scale
// =====================================================================
template<int BN, int MODE>
__global__ __launch_bounds__(512, 2) void gemm8_k(
    const u16* __restrict__ A, int lda, const u16* __restrict__ B, int ldb,
    float* __restrict__ Cf, u16* __restrict__ Cb,
    const float* __restrict__ bias, int ldc, int K, size_t zCstride, float scale)
{
    constexpr int NFRAG = BN / 64;          // n-fragments per wave
    constexpr int BKH   = BN * 32;          // B per-kh elems
    constexpr int BUFE  = 16384 + BN * 64;  // elems per buffer (A 2kh + B 2kh)
    __shared__ u16 lds[2 * BUFE];

    const int tid  = threadIdx.x;
    const int lane = tid & 63, wid = tid >> 6;
    const int wr = wid >> 2, wc = wid & 3;
    const int fr = lane & 15, fg = lane >> 4;

    const int gx  = gridDim.x, nwg = gx * gridDim.y;
    const int bid = blockIdx.y * gx + blockIdx.x;
    const int wg  = (bid & 7) * (nwg >> 3) + (bid >> 3);   // XCD-contiguous
    const int n0  = (wg % gx) * BN, m0 = (wg / gx) * 256;

    const u16* Az = A + (size_t)blockIdx.z * K;
    const u16* Bz = B + (size_t)blockIdx.z * K;
    float* Cfz = Cf ? Cf + (size_t)blockIdx.z * zCstride : nullptr;

    // staging geometry: thread covers row sr (and sr+128 for 256-row tiles)
    const int sr = tid >> 2;
    const int kb = ((tid & 3) ^ ((sr >> 1) & 3)) * 8;   // pre-swizzled col

    f32x4 acc[8][NFRAG];
    {
        f32x4 z = {0.f, 0.f, 0.f, 0.f};
        #pragma unroll
        for (int m = 0; m < 8; m++)
            #pragma unroll
            for (int n = 0; n < NFRAG; n++) acc[m][n] = z;
    }

    const int NT = K >> 6;

    auto STAGE = [&](int buf, int isB, int kh, int kt) {
        const u16* s0 = isB ? Bz : Az;
        const int  ld = isB ? ldb : lda;
        const int  rb = isB ? n0 : m0;
        const int  k0 = kt * 64 + kh * 32 + kb;
        u16* dst = &lds[buf * BUFE + (isB ? 16384 : 0) + kh * (isB ? BKH : 8192) + tid * 8];
        GLD16(s0 + (size_t)(rb + sr) * ld + k0, dst);
        if (!isB || BN == 256)
            GLD16(s0 + (size_t)(rb + 128 + sr) * ld + k0, dst + 4096);
    };

    #define CKPT_MID() do { if constexpr (BN == 256) asm volatile("s_waitcnt vmcnt(4)" ::: "memory"); \
                            else                     asm volatile("s_waitcnt vmcnt(3)" ::: "memory"); } while (0)

    // per-lane read bases (u16 units)
    const int swz   = (fg ^ ((fr >> 1) & 3)) * 8;
    const int baseA = (wr * 128 + fr) * 32 + swz;
    const int baseB = 16384 + (wc * (BN / 4) + fr) * 32 + swz;

    // prologue: A-kh0, B-kh0, A-kh1, B-kh1 of tile 0
    STAGE(0, 0, 0, 0); STAGE(0, 1, 0, 0); STAGE(0, 0, 1, 0); STAGE(0, 1, 1, 0);
    CKPT_MID();                                            // kh0 group landed
    __builtin_amdgcn_s_barrier();

    bf16x8 af[4], bv[NFRAG];

    for (int t = 0; t < NT; ++t) {
        const int  aO  = (t & 1) * BUFE;
        const int  nxt = (t & 1) ^ 1;
        const bool pre = (t + 1 < NT);

        // ---- phase 1: (ms=0, ks=0)
        #pragma unroll
        for (int m = 0; m < 4; m++) af[m] = *(const bf16x8*)&lds[baseA + aO + m * 512];
        #pragma unroll
        for (int n = 0; n < NFRAG; n++) bv[n] = *(const bf16x8*)&lds[baseB + aO + n * 512];
        if (pre) STAGE(nxt, 0, 0, t + 1);
        __builtin_amdgcn_s_barrier();
        asm volatile("s_waitcnt lgkmcnt(0)" ::: "memory");
        __builtin_amdgcn_sched_barrier(0);
        __builtin_amdgcn_s_setprio(1);
        #pragma unroll
        for (int m = 0; m < 4; m++)
            #pragma unroll
            for (int n = 0; n < NFRAG; n++)
                acc[m][n] = __builtin_amdgcn_mfma_f32_16x16x32_bf16(af[m], bv[n], acc[m][n], 0, 0, 0);
        __builtin_amdgcn_s_setprio(0);
        __builtin_amdgcn_s_barrier();

        // ---- phase 2: (ms=1, ks=0); ckpt kh1(t)
        #pragma unroll
        for (int m = 0; m < 4; m++) af[m] = *(const bf16x8*)&lds[baseA + aO + (4 + m) * 512];
        if (pre) STAGE(nxt, 1, 0, t + 1);
        __builtin_amdgcn_s_barrier();
        asm volatile("s_waitcnt lgkmcnt(0)" ::: "memory");
        __builtin_amdgcn_sched_barrier(0);
        __builtin_amdgcn_s_setprio(1);
        #pragma unroll
        for (int m = 0; m < 4; m++)
            #pragma unroll
            for (int n = 0; n < NFRAG; n++)
                acc[4 + m][n] = __builtin_amdgcn_mfma_f32_16x16x32_bf16(af[m], bv[n], acc[4 + m][n], 0, 0, 0);
        __builtin_amdgcn_s_setprio(0);
        if (pre) { CKPT_MID(); }
        else     { asm volatile("s_waitcnt vmcnt(0)" ::: "memory"); }
        __builtin_amdgcn_sched_barrier(0);
        __builtin_amdgcn_s_barrier();

        // ---- phase 3: (ms=0, ks=1)
        #pragma unroll
        for (int m = 0; m < 4; m++) af[m] = *(const bf16x8*)&lds[baseA + aO + 8192 + m * 512];
        #pragma unroll
        for (int n = 0; n < NFRAG; n++) bv[n] = *(const bf16x8*)&lds[baseB + aO + BKH + n * 512];
        if (pre) STAGE(nxt, 0, 1, t + 1);
        __builtin_amdgcn_s_barrier();
        asm volatile("s_waitcnt lgkmcnt(0)" ::: "memory");
        __builtin_amdgcn_sched_barrier(0);
        __builtin_amdgcn_s_setprio(1);
        #pragma unroll
        for (int m = 0; m < 4; m++)
            #pragma unroll
            for (int n = 0; n < NFRAG; n++)
                acc[m][n] = __builtin_amdgcn_mfma_f32_16x16x32_bf16(af[m], bv[n], acc[m][n], 0, 0, 0);
        __builtin_amdgcn_s_setprio(0);
        __builtin_amdgcn_s_barrier();

        // ---- phase 4: (ms=1, ks=1); ckpt kh0(t+1)
        #pragma unroll
        for (int m = 0; m < 4; m++) af[m] = *(const bf16x8*)&lds[baseA + aO + 8192 + (4 + m) * 512];
        if (pre) STAGE(nxt, 1, 1, t + 1);
        __builtin_amdgcn_s_barrier();
        asm volatile("s_waitcnt lgkmcnt(0)" ::: "memory");
        __builtin_amdgcn_sched_barrier(0);
        __builtin_amdgcn_s_setprio(1);
        #pragma unroll
        for (int m = 0; m < 4; m++)
            #pragma unroll
            for (int n = 0; n < NFRAG; n++)
                acc[4 + m][n] = __builtin_amdgcn_mfma_f32_16x16x32_bf16(af[m], bv[n], acc[4 + m][n], 0, 0, 0);
        __builtin_amdgcn_s_setprio(0);
        if (pre) { CKPT_MID(); }
        __builtin_amdgcn_sched_barrier(0);
        __builtin_amdgcn_s_barrier();
    }
    #undef CKPT_MID

    // epilogue: D layout col = lane&15, row = (lane>>4)*4 + reg [HW-verified]
    #pragma unroll
    for (int m = 0; m < 8; m++)
        #pragma unroll
        for (int n = 0; n < NFRAG; n++)
            #pragma unroll
            for (int r = 0; r < 4; r++) {
                int row = m0 + wr * 128 + m * 16 + fg * 4 + r;
                int col = n0 + wc * (BN / 4) + n * 16 + fr;
                size_t idx = (size_t)row * ldc + col;
                float v = acc[m][n][r] * scale;
                if (MODE == 0) {
                    Cfz[idx] = v;
                } else if (MODE == 1) {
                    Cfz[idx] = fmaxf(v + bias[col], 0.f);
                } else if (MODE == 2) {
                    Cfz[idx] += fmaxf(v + bias[col], 0.f);
                } else {
                    Cb[idx] = f2bf(v);
                }
            }
}

// ---------------- elementwise / converts ----------------
__global__ __launch_bounds__(256) void cvt_k(const float* __restrict__ s, u16* __restrict__ d) {
    int i = blockIdx.x * 256 + threadIdx.x;
    const float4* sf = reinterpret_cast<const float4*>(s);
    float4 a = sf[2 * i], b = sf[2 * i + 1];
    union { u16 u[8]; int4 v; } t;
    t.u[0] = f2bf(a.x); t.u[1] = f2bf(a.y); t.u[2] = f2bf(a.z); t.u[3] = f2bf(a.w);
    t.u[4] = f2bf(b.x); t.u[5] = f2bf(b.y); t.u[6] = f2bf(b.z); t.u[7] = f2bf(b.w);
    reinterpret_cast<int4*>(d)[i] = t.v;
}

// six 1024x1024 weight converts in one dispatch (grid 3072)
__global__ __launch_bounds__(256) void cvt6_k(
    const float* __restrict__ s0, const float* __restrict__ s1, const float* __restrict__ s2,
    const float* __restrict__ s3, const float* __restrict__ s4, const float* __restrict__ s5,
    u16* __restrict__ d0, u16* __restrict__ d1, u16* __restrict__ d2,
    u16* __restrict__ d3, u16* __restrict__ d4, u16* __restrict__ d5) {
    int w = blockIdx.x >> 9;
    const float* s = (w == 0) ? s0 : (w == 1) ? s1 : (w == 2) ? s2 : (w == 3) ? s3 : (w == 4) ? s4 : s5;
    u16*         d = (w == 0) ? d0 : (w == 1) ? d1 : (w == 2) ? d2 : (w == 3) ? d3 : (w == 4) ? d4 : d5;
    int i = (blockIdx.x & 511) * 256 + threadIdx.x;
    const float4* sf = reinterpret_cast<const float4*>(s);
    float4 a = sf[2 * i], b = sf[2 * i + 1];
    union { u16 u[8]; int4 v; } t;
    t.u[0] = f2bf(a.x); t.u[1] = f2bf(a.y); t.u[2] = f2bf(a.z); t.u[3] = f2bf(a.w);
    t.u[4] = f2bf(b.x); t.u[5] = f2bf(b.y); t.u[6] = f2bf(b.z); t.u[7] = f2bf(b.w);
    reinterpret_cast<int4*>(d)[i] = t.v;
}

// yb = bf16(y0 + y1)  (split-K PV reduction fused into the convert)
__global__ __launch_bounds__(256) void cvt2_k(const float* __restrict__ s0, const float* __restrict__ s1,
                                              u16* __restrict__ d) {
    int i = blockIdx.x * 256 + threadIdx.x;
    const float4* f0 = reinterpret_cast<const float4*>(s0);
    const float4* f1 = reinterpret_cast<const float4*>(s1);
    float4 a = f0[2 * i], b = f0[2 * i + 1];
    float4 c = f1[2 * i], e = f1[2 * i + 1];
    union { u16 u[8]; int4 v; } t;
    t.u[0] = f2bf(a.x + c.x); t.u[1] = f2bf(a.y + c.y);
    t.u[2] = f2bf(a.z + c.z); t.u[3] = f2bf(a.w + c.w);
    t.u[4] = f2bf(b.x + e.x); t.u[5] = f2bf(b.y + e.y);
    t.u[6] = f2bf(b.z + e.z); t.u[7] = f2bf(b.w + e.w);
    reinterpret_cast<int4*>(d)[i] = t.v;
}

// fused shifted-diffs: d1/d2/d3[i][:] = bf16(|x[i+{1,2,4}][:] - x[i][:]|), rows>=8188 zero
__global__ __launch_bounds__(256) void diff3_k(const float* __restrict__ x,
                                               u16* __restrict__ d1, u16* __restrict__ d2,
                                               u16* __restrict__ d3) {
    int i4 = blockIdx.x * 256 + threadIdx.x;    // float4 index; 256 per row
    int row = i4 >> 8;
    const float4* xf = reinterpret_cast<const float4*>(x);
    ushort4 o1, o2, o3;
    if (row < 8188) {
        float4 b  = xf[i4];
        float4 a1 = xf[i4 + (1 << 8)];
        float4 a2 = xf[i4 + (2 << 8)];
        float4 a3 = xf[i4 + (4 << 8)];
        o1.x = f2bf(fabsf(a1.x - b.x)); o1.y = f2bf(fabsf(a1.y - b.y));
        o1.z = f2bf(fabsf(a1.z - b.z)); o1.w = f2bf(fabsf(a1.w - b.w));
        o2.x = f2bf(fabsf(a2.x - b.x)); o2.y = f2bf(fabsf(a2.y - b.y));
        o2.z = f2bf(fabsf(a2.z - b.z)); o2.w = f2bf(fabsf(a2.w - b.w));
        o3.x = f2bf(fabsf(a3.x - b.x)); o3.y = f2bf(fabsf(a3.y - b.y));
        o3.z = f2bf(fabsf(a3.z - b.z)); o3.w = f2bf(fabsf(a3.w - b.w));
    } else {
        o1.x = o1.y = o1.z = o1.w = 0;
        o2 = o1; o3 = o1;
    }
    reinterpret_cast<ushort4*>(d1)[i4] = o1;
    reinterpret_cast<ushort4*>(d2)[i4] = o2;
    reinterpret_cast<ushort4*>(d3)[i4] = o3;
}

__global__ __launch_bounds__(256) void tail_k(const float* __restrict__ x, float* __restrict__ mn) {
    int i = blockIdx.x * 256 + threadIdx.x;
    mn[8188 * 1024 + i] = x[8188 * 1024 + i];
}

// ---------------- softmax over a row of 8192 fp32 ----------------
__global__ __launch_bounds__(256) void softmax_k(const float* __restrict__ S,
                                                 float* __restrict__ aw, int row0) {
    __shared__ float red[4];
    int r = blockIdx.x, tid = threadIdx.x;
    const float4* src = reinterpret_cast<const float4*>(S + (size_t)r * 8192);
    float4 xv[8];
    float mx = -1e30f;
    #pragma unroll
    for (int j = 0; j < 8; j++) {
        xv[j] = src[tid + 256 * j];
        mx = fmaxf(mx, fmaxf(fmaxf(xv[j].x, xv[j].y), fmaxf(xv[j].z, xv[j].w)));
    }
    mx = blk_max(mx, red);
    float sum = 0.f;
    #pragma unroll
    for (int j = 0; j < 8; j++) {
        xv[j].x = __expf(xv[j].x - mx); sum += xv[j].x;
        xv[j].y = __expf(xv[j].y - mx); sum += xv[j].y;
        xv[j].z = __expf(xv[j].z - mx); sum += xv[j].z;
        xv[j].w = __expf(xv[j].w - mx); sum += xv[j].w;
    }
    sum = blk_sum(sum, red);
    float inv = 1.0f / sum;
    float4* dst = reinterpret_cast<float4*>(aw + (size_t)(row0 + r) * 8192);
    #pragma unroll
    for (int j = 0; j < 8; j++) {
        float4 o;
        o.x = xv[j].x * inv; o.y = xv[j].y * inv; o.z = xv[j].z * inv; o.w = xv[j].w * inv;
        dst[tid + 256 * j] = o;
    }
}

// ---------------- transposes (64x64 tiles) ----------------
__global__ __launch_bounds__(256) void transpose_f32_bf16(const float* __restrict__ src,
                                                          u16* __restrict__ dst) {
    __shared__ u16 t[64][72];
    int r0 = blockIdx.y * 64, c0 = blockIdx.x * 64;
    int tid = threadIdx.x;
    #pragma unroll
    for (int p = 0; p < 4; p++) {
        int q = p * 256 + tid;
        int r = q >> 4, c4 = q & 15;
        float4 v = *(reinterpret_cast<const float4*>(src + (size_t)(r0 + r) * 8192 + c0) + c4);
        t[c4 * 4 + 0][r] = f2bf(v.x);
        t[c4 * 4 + 1][r] = f2bf(v.y);
        t[c4 * 4 + 2][r] = f2bf(v.z);
        t[c4 * 4 + 3][r] = f2bf(v.w);
    }
    __syncthreads();
    #pragma unroll
    for (int p = 0; p < 2; p++) {
        int q = p * 256 + tid;
        int rr = q >> 3, cc = q & 7;
        *reinterpret_cast<int4*>(dst + (size_t)(c0 + rr) * 8192 + r0 + cc * 8) =
            *reinterpret_cast<const int4*>(&t[rr][cc * 8]);
    }
}

// bf16 transpose with leading dims; grid (srccols/64, srcrows/64)
__global__ __launch_bounds__(256) void transpose_bf16(const u16* __restrict__ src,
                                                      u16* __restrict__ dst,
                                                      int srcld, int dstld) {
    __shared__ u16 t[64][72];
    int r0 = blockIdx.y * 64, c0 = blockIdx.x * 64;
    int tid = threadIdx.x;
    #pragma unroll
    for (int p = 0; p < 2; p++) {
        int q = p * 256 + tid;
        int r = q >> 3, c8 = q & 7;
        int4 v = *(reinterpret_cast<const int4*>(src + (size_t)(r0 + r) * srcld + c0) + c8);
        const u16* u = reinterpret_cast<const u16*>(&v);
        #pragma unroll
        for (int k = 0; k < 8; k++) t[c8 * 8 + k][r] = u[k];
    }
    __syncthreads();
    #pragma unroll
    for (int p = 0; p < 2; p++) {
        int q = p * 256 + tid;
        int rr = q >> 3, cc = q & 7;
        *reinterpret_cast<int4*>(dst + (size_t)(c0 + rr) * dstld + r0 + cc * 8) =
            *reinterpret_cast<const int4*>(&t[rr][cc * 8]);
    }
}

// ---------------- LN kernels ----------------
__global__ __launch_bounds__(256) void ln_y_k(const float* __restrict__ y2, const float* __restrict__ mn,
                                              const float* __restrict__ g, const float* __restrict__ b,
                                              u16* __restrict__ zb) {
    __shared__ float red[4];
    int r = blockIdx.x, tid = threadIdx.x;
    float4 a = reinterpret_cast<const float4*>(y2 + (size_t)r * 1024)[tid];
    float4 c = reinterpret_cast<const float4*>(mn + (size_t)r * 1024)[tid];
    float4 v; v.x = a.x + c.x; v.y = a.y + c.y; v.z = a.z + c.z; v.w = a.w + c.w;
    float s  = v.x + v.y + v.z + v.w;
    float sq = v.x * v.x + v.y * v.y + v.z * v.z + v.w * v.w;
    s  = blk_sum(s, red);
    sq = blk_sum(sq, red);
    float mu = s * (1.0f / 1024.0f);
    float rs = rsqrtf(sq * (1.0f / 1024.0f) - mu * mu + LN_EPS);
    float4 gg = reinterpret_cast<const float4*>(g)[tid];
    float4 bb = reinterpret_cast<const float4*>(b)[tid];
    ushort4 o;
    o.x = f2bf((v.x - mu) * rs * gg.x + bb.x);
    o.y = f2bf((v.y - mu) * rs * gg.y + bb.y);
    o.z = f2bf((v.z - mu) * rs * gg.z + bb.z);
    o.w = f2bf((v.w - mu) * rs * gg.w + bb.w);
    reinterpret_cast<ushort4*>(zb + (size_t)r * 1024)[tid] = o;
}

__global__ __launch_bounds__(256) void ln_dot_k(const float* __restrict__ h, const float* __restrict__ g,
                                                const float* __restrict__ b, const float* __restrict__ kd,
                                                const float* __restrict__ kdb, float* __restrict__ out) {
    __shared__ float red[4];
    int r = blockIdx.x, tid = threadIdx.x;
    float4 v = reinterpret_cast<const float4*>(h + (size_t)r * 1024)[tid];
    float s  = v.x + v.y + v.z + v.w;
    float sq = v.x * v.x + v.y * v.y + v.z * v.z + v.w * v.w;
    s  = blk_sum(s, red);
    sq = blk_sum(sq, red);
    float mu = s * (1.0f / 1024.0f);
    float rs = rsqrtf(sq * (1.0f / 1024.0f) - mu * mu + LN_EPS);
    float4 gg = reinterpret_cast<const float4*>(g)[tid];
    float4 bb = reinterpret_cast<const float4*>(b)[tid];
    float4 kk = reinterpret_cast<const float4*>(kd)[tid];
    float part = ((v.x - mu) * rs * gg.x + bb.x) * kk.x
               + ((v.y - mu) * rs * gg.y + bb.y) * kk.y
               + ((v.z - mu) * rs * gg.z + bb.z) * kk.z
               + ((v.w - mu) * rs * gg.w + bb.w) * kk.w;
    part = blk_sum(part, red);
    if (tid == 0) out[r] = 1.0f / (1.0f + __expf(-(part + kdb[0])));
}

// ---------------- launch ----------------
extern "C" void kernel_launch(void* const* d_in, const int* in_sizes, int n_in,
                              void* d_out, int out_size, void* d_ws, size_t ws_size,
                              hipStream_t stream) {
    (void)in_sizes; (void)n_in; (void)out_size; (void)ws_size;
    const float* x    = (const float*)d_in[0];
    const float* Wq   = (const float*)d_in[2];
    const float* Wk   = (const float*)d_in[3];
    const float* Wv   = (const float*)d_in[4];
    const float* Wo   = (const float*)d_in[5];
    const float* fc1w = (const float*)d_in[6];
    const float* fc1b = (const float*)d_in[7];
    const float* kaw  = (const float*)d_in[8];
    const float* kab  = (const float*)d_in[9];
    const float* kdw  = (const float*)d_in[10];
    const float* kdb  = (const float*)d_in[11];
    const float* lyg  = (const float*)d_in[12];
    const float* lyb  = (const float*)d_in[13];
    const float* lkg  = (const float*)d_in[14];
    const float* lkb  = (const float*)d_in[15];

    float* out0 = (float*)d_out;
    float* aw   = out0 + 8192;

    char* base = (char*)d_ws;
    size_t off = 0;
    auto alloc = [&](size_t bytes) -> char* {
        char* p = base + off;
        off += (bytes + 255) & ~(size_t)255;
        return p;
    };
    const size_t NM = 8192ULL * 1024ULL;
    u16*   ST   = (u16*)alloc(8192ULL * 8192ULL * 2);   // 128MB; fully aliases Sf (4096x8192 f32)
    float* Sf   = (float*)ST;
    u16*   xb   = (u16*)alloc(NM * 2);
    u16*   Qb   = (u16*)alloc(NM * 2);
    u16*   Kb   = (u16*)alloc(NM * 2);
    u16*   Vb   = (u16*)alloc(NM * 2);
    u16*   Vt   = (u16*)alloc(NM * 2);
    u16*   d1   = (u16*)alloc(NM * 2);                  // later reused as zb
    u16*   d2   = (u16*)alloc(NM * 2);
    u16*   d3   = (u16*)alloc(NM * 2);
    u16*   yb   = (u16*)alloc(NM * 2);
    float* mn   = (float*)alloc(NM * 4);
    float* y01  = (float*)alloc(NM * 4 * 2);            // PV split-K slices
    float* y2   = (float*)alloc(NM * 4);
    float* hbuf = (float*)alloc(NM * 4);
    u16*   Wqb  = (u16*)alloc(1048576ULL * 2);
    u16*   Wkb  = (u16*)alloc(1048576ULL * 2);
    u16*   Wvb  = (u16*)alloc(1048576ULL * 2);
    u16*   fwb  = (u16*)alloc(1048576ULL * 2);
    u16*   Wob  = (u16*)alloc(1048576ULL * 2);
    u16*   kwb  = (u16*)alloc(1048576ULL * 2);
    u16*   zb   = d1;

    // 1) converts (all plain bf16; logits error margin verified R7)
    cvt_k<<<4096, 256, 0, stream>>>(x, xb);
    cvt6_k<<<3072, 256, 0, stream>>>(Wq, Wk, Wv, fc1w, Wo, kaw,
                                     Wqb, Wkb, Wvb, fwb, Wob, kwb);

    // 2) mn branch: fused diff3 -> 3x BN=128 gemm8; tail rows
    diff3_k<<<8192, 256, 0, stream>>>(x, d1, d2, d3);
    gemm8_k<128, 1><<<dim3(8, 32), 512, 0, stream>>>(
        d1, 1024, fwb, 1024, mn, nullptr, fc1b, 1024, 1024, 0, 1.0f);
    gemm8_k<128, 2><<<dim3(8, 32), 512, 0, stream>>>(
        d2, 1024, fwb, 1024, mn, nullptr, fc1b, 1024, 1024, 0, 1.0f);
    gemm8_k<128, 2><<<dim3(8, 32), 512, 0, stream>>>(
        d3, 1024, fwb, 1024, mn, nullptr, fc1b, 1024, 1024, 0, 1.0f);
    tail_k<<<16, 256, 0, stream>>>(x, mn);

    // 3) projections: Q (x0.06), K, V — plain bf16 K=1024 GEMMs
    gemm8_k<128, 3><<<dim3(8, 32), 512, 0, stream>>>(
        xb, 1024, Wqb, 1024, nullptr, Qb, nullptr, 1024, 1024, 0, 0.06f);
    gemm8_k<128, 3><<<dim3(8, 32), 512, 0, stream>>>(
        xb, 1024, Wkb, 1024, nullptr, Kb, nullptr, 1024, 1024, 0, 1.0f);
    gemm8_k<128, 3><<<dim3(8, 32), 512, 0, stream>>>(
        xb, 1024, Wvb, 1024, nullptr, Vb, nullptr, 1024, 1024, 0, 1.0f);
    transpose_bf16<<<dim3(16, 128), 256, 0, stream>>>(Vb, Vt, 1024, 8192);

    // 4) logits = Q·K^T, 2 chunks of 4096 rows (Sf = 128MB = full ST alias)
    for (int c = 0; c < 2; ++c) {
        gemm8_k<256, 0><<<dim3(32, 16), 512, 0, stream>>>(
            Qb + (size_t)c * 4096 * 1024, 1024, Kb, 1024,
            Sf, nullptr, nullptr, 8192, 1024, 0, 1.0f);
        softmax_k<<<4096, 256, 0, stream>>>(Sf, aw, c * 4096);
    }

    // 5) ST = aw^T (bf16); PV split-K z=2 (BN=256): y01 slices; yb = bf16(y0+y1)
    transpose_f32_bf16<<<dim3(128, 128), 256, 0, stream>>>(aw, ST);
    gemm8_k<256, 0><<<dim3(4, 32, 2), 512, 0, stream>>>(
        ST, 8192, Vt, 8192, y01, nullptr, nullptr, 1024, 4096, NM, 1.0f);
    cvt2_k<<<4096, 256, 0, stream>>>(y01, y01 + NM, yb);

    // 6) head: y2 = yb@Wo^T ; zb = LN(y2+mn) ; h = relu(zb@ka^T+b) ; out
    gemm8_k<128, 0><<<dim3(8, 32), 512, 0, stream>>>(
        yb, 1024, Wob, 1024, y2, nullptr, nullptr, 1024, 1024, 0, 1.0f);
    ln_y_k<<<8192, 256, 0, stream>>>(y2, mn, lyg, lyb, zb);
    gemm8_k<128, 1><<<dim3(8, 32), 512, 0, stream>>>(
        zb, 1024, kwb, 1024, hbuf, nullptr, kab, 1024, 1024, 0, 1.0f);
    ln_dot_k<<<8192, 256, 0, stream>>>(hbuf, lkg, lkb, kdw, kdb, out0);
}

// Round 9
// 775.745 us; speedup vs baseline: 2.0644x; 1.0112x over previous
//
#include <hip/hip_runtime.h>
#include <cstdint>
#include <cstddef>

typedef unsigned short u16;
typedef short bf16x8 __attribute__((ext_vector_type(8)));
typedef float f32x4 __attribute__((ext_vector_type(4)));

#define LN_EPS 1e-6f

// async global->LDS, 16B per lane; LDS dest is wave-uniform base + lane*16
#define GLD16(gsrc, ldst) \
    __builtin_amdgcn_global_load_lds( \
        (const __attribute__((address_space(1))) void*)(gsrc), \
        (__attribute__((address_space(3))) void*)(ldst), 16, 0, 0)

__device__ inline u16 f2bf(float f) {
    uint32_t x = __float_as_uint(f);
    uint32_t r = (x + 0x7fffu + ((x >> 16) & 1u)) >> 16;   // RNE
    return (u16)r;
}
__device__ inline float bf2f(u16 u) { return __uint_as_float(((uint32_t)u) << 16); }

// ---------------- block reductions (256 threads = 4 waves) ----------------
__device__ inline float blk_sum(float v, float* s) {
    #pragma unroll
    for (int o = 32; o > 0; o >>= 1) v += __shfl_xor(v, o);
    __syncthreads();
    if ((threadIdx.x & 63) == 0) s[threadIdx.x >> 6] = v;
    __syncthreads();
    return s[0] + s[1] + s[2] + s[3];
}
__device__ inline float blk_max(float v, float* s) {
    #pragma unroll
    for (int o = 32; o > 0; o >>= 1) v = fmaxf(v, __shfl_xor(v, o));
    __syncthreads();
    if ((threadIdx.x & 63) == 0) s[threadIdx.x >> 6] = v;
    __syncthreads();
    return fmaxf(fmaxf(s[0], s[1]), fmaxf(s[2], s[3]));
}

// =====================================================================
// 8-phase 256xBN GEMM (m201-template port; validated R3/R5-R8).
// C[m][n] = sum_k A[m][k]*B[n][k], row-major k-contiguous.
// BN in {256,128}: 8 waves as 2(M)x4(N), per-wave 128 x BN/4.
// BK=64 staged as 2 k-halves; double-buffered LDS; counted vmcnt ckpts
// (4 for BN=256, 3 for BN=128) at phases 2/4 — never drain-0 mid-loop.
// LDS 16B-slot swizzle on global SOURCE col + ds_read addr (rule #21).
// Grid (N/BN, M/256, Z); Z split-K: A,B advance z*K elems, C advances
// z*zCstride floats. gridDim.x*gridDim.y % 8 == 0; use 256 blocks/round.
// MODE: 0 f32*scale | 1 f32 relu(acc+bias) | 2 f32 += relu(acc+bias)
//       | 3 bf16*scale
// =====================================================================
template<int BN, int MODE>
__global__ __launch_bounds__(512, 2) void gemm8_k(
    const u16* __restrict__ A, int lda, const u16* __restrict__ B, int ldb,
    float* __restrict__ Cf, u16* __restrict__ Cb,
    const float* __restrict__ bias, int ldc, int K, size_t zCstride, float scale)
{
    constexpr int NFRAG = BN / 64;          // n-fragments per wave
    constexpr int BKH   = BN * 32;          // B per-kh elems
    constexpr int BUFE  = 16384 + BN * 64;  // elems per buffer (A 2kh + B 2kh)
    __shared__ u16 lds[2 * BUFE];

    const int tid  = threadIdx.x;
    const int lane = tid & 63, wid = tid >> 6;
    const int wr = wid >> 2, wc = wid & 3;
    const int fr = lane & 15, fg = lane >> 4;

    const int gx  = gridDim.x, nwg = gx * gridDim.y;
    const int bid = blockIdx.y * gx + blockIdx.x;
    const int wg  = (bid & 7) * (nwg >> 3) + (bid >> 3);   // XCD-contiguous
    const int n0  = (wg % gx) * BN, m0 = (wg / gx) * 256;

    const u16* Az = A + (size_t)blockIdx.z * K;
    const u16* Bz = B + (size_t)blockIdx.z * K;
    float* Cfz = Cf ? Cf + (size_t)blockIdx.z * zCstride : nullptr;

    // staging geometry: thread covers row sr (and sr+128 for 256-row tiles)
    const int sr = tid >> 2;
    const int kb = ((tid & 3) ^ ((sr >> 1) & 3)) * 8;   // pre-swizzled col

    f32x4 acc[8][NFRAG];
    {
        f32x4 z = {0.f, 0.f, 0.f, 0.f};
        #pragma unroll
        for (int m = 0; m < 8; m++)
            #pragma unroll
            for (int n = 0; n < NFRAG; n++) acc[m][n] = z;
    }

    const int NT = K >> 6;

    auto STAGE = [&](int buf, int isB, int kh, int kt) {
        const u16* s0 = isB ? Bz : Az;
        const int  ld = isB ? ldb : lda;
        const int  rb = isB ? n0 : m0;
        const int  k0 = kt * 64 + kh * 32 + kb;
        u16* dst = &lds[buf * BUFE + (isB ? 16384 : 0) + kh * (isB ? BKH : 8192) + tid * 8];
        GLD16(s0 + (size_t)(rb + sr) * ld + k0, dst);
        if (!isB || BN == 256)
            GLD16(s0 + (size_t)(rb + 128 + sr) * ld + k0, dst + 4096);
    };

    #define CKPT_MID() do { if constexpr (BN == 256) asm volatile("s_waitcnt vmcnt(4)" ::: "memory"); \
                            else                     asm volatile("s_waitcnt vmcnt(3)" ::: "memory"); } while (0)

    // per-lane read bases (u16 units)
    const int swz   = (fg ^ ((fr >> 1) & 3)) * 8;
    const int baseA = (wr * 128 + fr) * 32 + swz;
    const int baseB = 16384 + (wc * (BN / 4) + fr) * 32 + swz;

    // prologue: A-kh0, B-kh0, A-kh1, B-kh1 of tile 0
    STAGE(0, 0, 0, 0); STAGE(0, 1, 0, 0); STAGE(0, 0, 1, 0); STAGE(0, 1, 1, 0);
    CKPT_MID();                                            // kh0 group landed
    __builtin_amdgcn_s_barrier();

    bf16x8 af[4], bv[NFRAG];

    for (int t = 0; t < NT; ++t) {
        const int  aO  = (t & 1) * BUFE;
        const int  nxt = (t & 1) ^ 1;
        const bool pre = (t + 1 < NT);

        // ---- phase 1: (ms=0, ks=0)
        #pragma unroll
        for (int m = 0; m < 4; m++) af[m] = *(const bf16x8*)&lds[baseA + aO + m * 512];
        #pragma unroll
        for (int n = 0; n < NFRAG; n++) bv[n] = *(const bf16x8*)&lds[baseB + aO + n * 512];
        if (pre) STAGE(nxt, 0, 0, t + 1);
        __builtin_amdgcn_s_barrier();
        asm volatile("s_waitcnt lgkmcnt(0)" ::: "memory");
        __builtin_amdgcn_sched_barrier(0);
        __builtin_amdgcn_s_setprio(1);
        #pragma unroll
        for (int m = 0; m < 4; m++)
            #pragma unroll
            for (int n = 0; n < NFRAG; n++)
                acc[m][n] = __builtin_amdgcn_mfma_f32_16x16x32_bf16(af[m], bv[n], acc[m][n], 0, 0, 0);
        __builtin_amdgcn_s_setprio(0);
        __builtin_amdgcn_s_barrier();

        // ---- phase 2: (ms=1, ks=0); ckpt kh1(t)
        #pragma unroll
        for (int m = 0; m < 4; m++) af[m] = *(const bf16x8*)&lds[baseA + aO + (4 + m) * 512];
        if (pre) STAGE(nxt, 1, 0, t + 1);
        __builtin_amdgcn_s_barrier();
        asm volatile("s_waitcnt lgkmcnt(0)" ::: "memory");
        __builtin_amdgcn_sched_barrier(0);
        __builtin_amdgcn_s_setprio(1);
        #pragma unroll
        for (int m = 0; m < 4; m++)
            #pragma unroll
            for (int n = 0; n < NFRAG; n++)
                acc[4 + m][n] = __builtin_amdgcn_mfma_f32_16x16x32_bf16(af[m], bv[n], acc[4 + m][n], 0, 0, 0);
        __builtin_amdgcn_s_setprio(0);
        if (pre) { CKPT_MID(); }
        else     { asm volatile("s_waitcnt vmcnt(0)" ::: "memory"); }
        __builtin_amdgcn_sched_barrier(0);
        __builtin_amdgcn_s_barrier();

        // ---- phase 3: (ms=0, ks=1)
        #pragma unroll
        for (int m = 0; m < 4; m++) af[m] = *(const bf16x8*)&lds[baseA + aO + 8192 + m * 512];
        #pragma unroll
        for (int n = 0; n < NFRAG; n++) bv[n] = *(const bf16x8*)&lds[baseB + aO + BKH + n * 512];
        if (pre) STAGE(nxt, 0, 1, t + 1);
        __builtin_amdgcn_s_barrier();
        asm volatile("s_waitcnt lgkmcnt(0)" ::: "memory");
        __builtin_amdgcn_sched_barrier(0);
        __builtin_amdgcn_s_setprio(1);
        #pragma unroll
        for (int m = 0; m < 4; m++)
            #pragma unroll
            for (int n = 0; n < NFRAG; n++)
                acc[m][n] = __builtin_amdgcn_mfma_f32_16x16x32_bf16(af[m], bv[n], acc[m][n], 0, 0, 0);
        __builtin_amdgcn_s_setprio(0);
        __builtin_amdgcn_s_barrier();

        // ---- phase 4: (ms=1, ks=1); ckpt kh0(t+1)
        #pragma unroll
        for (int m = 0; m < 4; m++) af[m] = *(const bf16x8*)&lds[baseA + aO + 8192 + (4 + m) * 512];
        if (pre) STAGE(nxt, 1, 1, t + 1);
        __builtin_amdgcn_s_barrier();
        asm volatile("s_waitcnt lgkmcnt(0)" ::: "memory");
        __builtin_amdgcn_sched_barrier(0);
        __builtin_amdgcn_s_setprio(1);
        #pragma unroll
        for (int m = 0; m < 4; m++)
            #pragma unroll
            for (int n = 0; n < NFRAG; n++)
                acc[4 + m][n] = __builtin_amdgcn_mfma_f32_16x16x32_bf16(af[m], bv[n], acc[4 + m][n], 0, 0, 0);
        __builtin_amdgcn_s_setprio(0);
        if (pre) { CKPT_MID(); }
        __builtin_amdgcn_sched_barrier(0);
        __builtin_amdgcn_s_barrier();
    }
    #undef CKPT_MID

    // epilogue: D layout col = lane&15, row = (lane>>4)*4 + reg [HW-verified]
    #pragma unroll
    for (int m = 0; m < 8; m++)
        #pragma unroll
        for (int n = 0; n < NFRAG; n++)
            #pragma unroll
            for (int r = 0; r < 4; r++) {
                int row = m0 + wr * 128 + m * 16 + fg * 4 + r;
                int col = n0 + wc * (BN / 4) + n * 16 + fr;
                size_t idx = (size_t)row * ldc + col;
                float v = acc[m][n][r] * scale;
                if (MODE == 0) {
                    Cfz[idx] = v;
                } else if (MODE == 1) {
                    Cfz[idx] = fmaxf(v + bias[col], 0.f);
                } else if (MODE == 2) {
                    Cfz[idx] += fmaxf(v + bias[col], 0.f);
                } else {
                    Cb[idx] = f2bf(v);
                }
            }
}

// ---------------- elementwise / converts ----------------
// six 1024x1024 weight converts in one dispatch (grid 3072)
__global__ __launch_bounds__(256) void cvt6_k(
    const float* __restrict__ s0, const float* __restrict__ s1, const float* __restrict__ s2,
    const float* __restrict__ s3, const float* __restrict__ s4, const float* __restrict__ s5,
    u16* __restrict__ d0, u16* __restrict__ d1, u16* __restrict__ d2,
    u16* __restrict__ d3, u16* __restrict__ d4, u16* __restrict__ d5) {
    int w = blockIdx.x >> 9;
    const float* s = (w == 0) ? s0 : (w == 1) ? s1 : (w == 2) ? s2 : (w == 3) ? s3 : (w == 4) ? s4 : s5;
    u16*         d = (w == 0) ? d0 : (w == 1) ? d1 : (w == 2) ? d2 : (w == 3) ? d3 : (w == 4) ? d4 : d5;
    int i = (blockIdx.x & 511) * 256 + threadIdx.x;
    const float4* sf = reinterpret_cast<const float4*>(s);
    float4 a = sf[2 * i], b = sf[2 * i + 1];
    union { u16 u[8]; int4 v; } t;
    t.u[0] = f2bf(a.x); t.u[1] = f2bf(a.y); t.u[2] = f2bf(a.z); t.u[3] = f2bf(a.w);
    t.u[4] = f2bf(b.x); t.u[5] = f2bf(b.y); t.u[6] = f2bf(b.z); t.u[7] = f2bf(b.w);
    reinterpret_cast<int4*>(d)[i] = t.v;
}

// yb = bf16(y0 + y1)  (split-K PV reduction fused into the convert)
__global__ __launch_bounds__(256) void cvt2_k(const float* __restrict__ s0, const float* __restrict__ s1,
                                              u16* __restrict__ d) {
    int i = blockIdx.x * 256 + threadIdx.x;
    const float4* f0 = reinterpret_cast<const float4*>(s0);
    const float4* f1 = reinterpret_cast<const float4*>(s1);
    float4 a = f0[2 * i], b = f0[2 * i + 1];
    float4 c = f1[2 * i], e = f1[2 * i + 1];
    union { u16 u[8]; int4 v; } t;
    t.u[0] = f2bf(a.x + c.x); t.u[1] = f2bf(a.y + c.y);
    t.u[2] = f2bf(a.z + c.z); t.u[3] = f2bf(a.w + c.w);
    t.u[4] = f2bf(b.x + e.x); t.u[5] = f2bf(b.y + e.y);
    t.u[6] = f2bf(b.z + e.z); t.u[7] = f2bf(b.w + e.w);
    reinterpret_cast<int4*>(d)[i] = t.v;
}

// fused: xb = bf16(x); d1/d2/d3 = bf16(|x[i+{1,2,4}] - x[i]|) (rows>=8188 zero)
__global__ __launch_bounds__(256) void diff3x_k(const float* __restrict__ x,
                                                u16* __restrict__ d1, u16* __restrict__ d2,
                                                u16* __restrict__ d3, u16* __restrict__ xb) {
    int i4 = blockIdx.x * 256 + threadIdx.x;    // float4 index; 256 per row
    int row = i4 >> 8;
    const float4* xf = reinterpret_cast<const float4*>(x);
    float4 b = xf[i4];
    ushort4 ox;
    ox.x = f2bf(b.x); ox.y = f2bf(b.y); ox.z = f2bf(b.z); ox.w = f2bf(b.w);
    reinterpret_cast<ushort4*>(xb)[i4] = ox;
    ushort4 o1, o2, o3;
    if (row < 8188) {
        float4 a1 = xf[i4 + (1 << 8)];
        float4 a2 = xf[i4 + (2 << 8)];
        float4 a3 = xf[i4 + (4 << 8)];
        o1.x = f2bf(fabsf(a1.x - b.x)); o1.y = f2bf(fabsf(a1.y - b.y));
        o1.z = f2bf(fabsf(a1.z - b.z)); o1.w = f2bf(fabsf(a1.w - b.w));
        o2.x = f2bf(fabsf(a2.x - b.x)); o2.y = f2bf(fabsf(a2.y - b.y));
        o2.z = f2bf(fabsf(a2.z - b.z)); o2.w = f2bf(fabsf(a2.w - b.w));
        o3.x = f2bf(fabsf(a3.x - b.x)); o3.y = f2bf(fabsf(a3.y - b.y));
        o3.z = f2bf(fabsf(a3.z - b.z)); o3.w = f2bf(fabsf(a3.w - b.w));
    } else {
        o1.x = o1.y = o1.z = o1.w = 0;
        o2 = o1; o3 = o1;
    }
    reinterpret_cast<ushort4*>(d1)[i4] = o1;
    reinterpret_cast<ushort4*>(d2)[i4] = o2;
    reinterpret_cast<ushort4*>(d3)[i4] = o3;
}

__global__ __launch_bounds__(256) void tail_k(const float* __restrict__ x, float* __restrict__ mn) {
    int i = blockIdx.x * 256 + threadIdx.x;
    mn[8188 * 1024 + i] = x[8188 * 1024 + i];
}

// ---------------- softmax row stats: m = rowmax, linv = 1/sum(exp(x-m)) ----------------
__global__ __launch_bounds__(256) void stats_k(const float* __restrict__ S,
                                               float* __restrict__ rowm, float* __restrict__ rowl) {
    __shared__ float red[4];
    int r = blockIdx.x, tid = threadIdx.x;
    const float4* src = reinterpret_cast<const float4*>(S + (size_t)r * 8192);
    float4 xv[8];
    float mx = -1e30f;
    #pragma unroll
    for (int j = 0; j < 8; j++) {
        xv[j] = src[tid + 256 * j];
        mx = fmaxf(mx, fmaxf(fmaxf(xv[j].x, xv[j].y), fmaxf(xv[j].z, xv[j].w)));
    }
    mx = blk_max(mx, red);
    float sum = 0.f;
    #pragma unroll
    for (int j = 0; j < 8; j++) {
        sum += __expf(xv[j].x - mx) + __expf(xv[j].y - mx)
             + __expf(xv[j].z - mx) + __expf(xv[j].w - mx);
    }
    sum = blk_sum(sum, red);
    if (tid == 0) { rowm[r] = mx; rowl[r] = 1.0f / sum; }
}

// ---------------- fused normalize + dual-write (aw f32 rows, ST bf16 transposed) ----
// Sf chunk is 4096x8192; aw rows at awc; ST cols at colbase. Grid (128, 64).
__global__ __launch_bounds__(256) void nt_k(const float* __restrict__ Sf,
                                            const float* __restrict__ rowm,
                                            const float* __restrict__ rowl,
                                            float* __restrict__ awc,
                                            u16* __restrict__ ST, int colbase) {
    __shared__ u16 t[64][72];
    int r0 = blockIdx.y * 64, c0 = blockIdx.x * 64;
    int tid = threadIdx.x;
    #pragma unroll
    for (int p = 0; p < 4; p++) {
        int q = p * 256 + tid;
        int r = q >> 4, c4 = q & 15;
        float4 v = *(reinterpret_cast<const float4*>(Sf + (size_t)(r0 + r) * 8192 + c0) + c4);
        float m  = rowm[r0 + r], li = rowl[r0 + r];
        float4 o;
        o.x = __expf(v.x - m) * li;
        o.y = __expf(v.y - m) * li;
        o.z = __expf(v.z - m) * li;
        o.w = __expf(v.w - m) * li;
        *(reinterpret_cast<float4*>(awc + (size_t)(r0 + r) * 8192 + c0) + c4) = o;
        t[c4 * 4 + 0][r] = f2bf(o.x);
        t[c4 * 4 + 1][r] = f2bf(o.y);
        t[c4 * 4 + 2][r] = f2bf(o.z);
        t[c4 * 4 + 3][r] = f2bf(o.w);
    }
    __syncthreads();
    #pragma unroll
    for (int p = 0; p < 2; p++) {
        int q = p * 256 + tid;
        int rr = q >> 3, cc = q & 7;
        *reinterpret_cast<int4*>(ST + (size_t)(c0 + rr) * 8192 + colbase + r0 + cc * 8) =
            *reinterpret_cast<const int4*>(&t[rr][cc * 8]);
    }
}

// bf16 transpose with leading dims; grid (srccols/64, srcrows/64)
__global__ __launch_bounds__(256) void transpose_bf16(const u16* __restrict__ src,
                                                      u16* __restrict__ dst,
                                                      int srcld, int dstld) {
    __shared__ u16 t[64][72];
    int r0 = blockIdx.y * 64, c0 = blockIdx.x * 64;
    int tid = threadIdx.x;
    #pragma unroll
    for (int p = 0; p < 2; p++) {
        int q = p * 256 + tid;
        int r = q >> 3, c8 = q & 7;
        int4 v = *(reinterpret_cast<const int4*>(src + (size_t)(r0 + r) * srcld + c0) + c8);
        const u16* u = reinterpret_cast<const u16*>(&v);
        #pragma unroll
        for (int k = 0; k < 8; k++) t[c8 * 8 + k][r] = u[k];
    }
    __syncthreads();
    #pragma unroll
    for (int p = 0; p < 2; p++) {
        int q = p * 256 + tid;
        int rr = q >> 3, cc = q & 7;
        *reinterpret_cast<int4*>(dst + (size_t)(c0 + rr) * dstld + r0 + cc * 8) =
            *reinterpret_cast<const int4*>(&t[rr][cc * 8]);
    }
}

// ---------------- LN kernels ----------------
__global__ __launch_bounds__(256) void ln_y_k(const float* __restrict__ y2, const float* __restrict__ mn,
                                              const float* __restrict__ g, const float* __restrict__ b,
                                              u16* __restrict__ zb) {
    __shared__ float red[4];
    int r = blockIdx.x, tid = threadIdx.x;
    float4 a = reinterpret_cast<const float4*>(y2 + (size_t)r * 1024)[tid];
    float4 c = reinterpret_cast<const float4*>(mn + (size_t)r * 1024)[tid];
    float4 v; v.x = a.x + c.x; v.y = a.y + c.y; v.z = a.z + c.z; v.w = a.w + c.w;
    float s  = v.x + v.y + v.z + v.w;
    float sq = v.x * v.x + v.y * v.y + v.z * v.z + v.w * v.w;
    s  = blk_sum(s, red);
    sq = blk_sum(sq, red);
    float mu = s * (1.0f / 1024.0f);
    float rs = rsqrtf(sq * (1.0f / 1024.0f) - mu * mu + LN_EPS);
    float4 gg = reinterpret_cast<const float4*>(g)[tid];
    float4 bb = reinterpret_cast<const float4*>(b)[tid];
    ushort4 o;
    o.x = f2bf((v.x - mu) * rs * gg.x + bb.x);
    o.y = f2bf((v.y - mu) * rs * gg.y + bb.y);
    o.z = f2bf((v.z - mu) * rs * gg.z + bb.z);
    o.w = f2bf((v.w - mu) * rs * gg.w + bb.w);
    reinterpret_cast<ushort4*>(zb + (size_t)r * 1024)[tid] = o;
}

__global__ __launch_bounds__(256) void ln_dot_k(const float* __restrict__ h, const float* __restrict__ g,
                                                const float* __restrict__ b, const float* __restrict__ kd,
                                                const float* __restrict__ kdb, float* __restrict__ out) {
    __shared__ float red[4];
    int r = blockIdx.x, tid = threadIdx.x;
    float4 v = reinterpret_cast<const float4*>(h + (size_t)r * 1024)[tid];
    float s  = v.x + v.y + v.z + v.w;
    float sq = v.x * v.x + v.y * v.y + v.z * v.z + v.w * v.w;
    s  = blk_sum(s, red);
    sq = blk_sum(sq, red);
    float mu = s * (1.0f / 1024.0f);
    float rs = rsqrtf(sq * (1.0f / 1024.0f) - mu * mu + LN_EPS);
    float4 gg = reinterpret_cast<const float4*>(g)[tid];
    float4 bb = reinterpret_cast<const float4*>(b)[tid];
    float4 kk = reinterpret_cast<const float4*>(kd)[tid];
    float part = ((v.x - mu) * rs * gg.x + bb.x) * kk.x
               + ((v.y - mu) * rs * gg.y + bb.y) * kk.y
               + ((v.z - mu) * rs * gg.z + bb.z) * kk.z
               + ((v.w - mu) * rs * gg.w + bb.w) * kk.w;
    part = blk_sum(part, red);
    if (tid == 0) out[r] = 1.0f / (1.0f + __expf(-(part + kdb[0])));
}

// ---------------- launch ----------------
extern "C" void kernel_launch(void* const* d_in, const int* in_sizes, int n_in,
                              void* d_out, int out_size, void* d_ws, size_t ws_size,
                              hipStream_t stream) {
    (void)in_sizes; (void)n_in; (void)out_size; (void)ws_size;
    const float* x    = (const float*)d_in[0];
    const float* Wq   = (const float*)d_in[2];
    const float* Wk   = (const float*)d_in[3];
    const float* Wv   = (const float*)d_in[4];
    const float* Wo   = (const float*)d_in[5];
    const float* fc1w = (const float*)d_in[6];
    const float* fc1b = (const float*)d_in[7];
    const float* kaw  = (const float*)d_in[8];
    const float* kab  = (const float*)d_in[9];
    const float* kdw  = (const float*)d_in[10];
    const float* kdb  = (const float*)d_in[11];
    const float* lyg  = (const float*)d_in[12];
    const float* lyb  = (const float*)d_in[13];
    const float* lkg  = (const float*)d_in[14];
    const float* lkb  = (const float*)d_in[15];

    float* out0 = (float*)d_out;
    float* aw   = out0 + 8192;

    char* base = (char*)d_ws;
    size_t off = 0;
    auto alloc = [&](size_t bytes) -> char* {
        char* p = base + off;
        off += (bytes + 255) & ~(size_t)255;
        return p;
    };
    const size_t NM = 8192ULL * 1024ULL;
    u16*   ST   = (u16*)alloc(8192ULL * 8192ULL * 2);   // 128MB aw^T bf16
    float* Sf   = (float*)alloc(4096ULL * 8192ULL * 4); // 128MB logits chunk (separate: nt reads Sf, writes ST)
    u16*   xb   = (u16*)alloc(NM * 2);
    u16*   Qb   = (u16*)alloc(NM * 2);
    u16*   Kb   = (u16*)alloc(NM * 2);
    u16*   Vb   = (u16*)alloc(NM * 2);
    u16*   Vt   = (u16*)alloc(NM * 2);
    u16*   d1   = (u16*)alloc(NM * 2);                  // later reused as zb
    u16*   d2   = (u16*)alloc(NM * 2);
    u16*   d3   = (u16*)alloc(NM * 2);
    u16*   yb   = (u16*)alloc(NM * 2);
    float* mn   = (float*)alloc(NM * 4);
    float* y01  = (float*)alloc(NM * 4 * 2);            // PV split-K slices
    float* y2   = (float*)alloc(NM * 4);
    float* hbuf = (float*)alloc(NM * 4);
    u16*   Wqb  = (u16*)alloc(1048576ULL * 2);
    u16*   Wkb  = (u16*)alloc(1048576ULL * 2);
    u16*   Wvb  = (u16*)alloc(1048576ULL * 2);
    u16*   fwb  = (u16*)alloc(1048576ULL * 2);
    u16*   Wob  = (u16*)alloc(1048576ULL * 2);
    u16*   kwb  = (u16*)alloc(1048576ULL * 2);
    float* rowm = (float*)alloc(4096ULL * 4);
    float* rowl = (float*)alloc(4096ULL * 4);
    u16*   zb   = d1;

    // 1) converts: x (+fused diffs) and 6 weights
    diff3x_k<<<8192, 256, 0, stream>>>(x, d1, d2, d3, xb);
    cvt6_k<<<3072, 256, 0, stream>>>(Wq, Wk, Wv, fc1w, Wo, kaw,
                                     Wqb, Wkb, Wvb, fwb, Wob, kwb);

    // 2) mn branch: 3x BN=128 gemm8; tail rows
    gemm8_k<128, 1><<<dim3(8, 32), 512, 0, stream>>>(
        d1, 1024, fwb, 1024, mn, nullptr, fc1b, 1024, 1024, 0, 1.0f);
    gemm8_k<128, 2><<<dim3(8, 32), 512, 0, stream>>>(
        d2, 1024, fwb, 1024, mn, nullptr, fc1b, 1024, 1024, 0, 1.0f);
    gemm8_k<128, 2><<<dim3(8, 32), 512, 0, stream>>>(
        d3, 1024, fwb, 1024, mn, nullptr, fc1b, 1024, 1024, 0, 1.0f);
    tail_k<<<16, 256, 0, stream>>>(x, mn);

    // 3) projections: Q (x0.06), K, V — plain bf16 K=1024 GEMMs
    gemm8_k<128, 3><<<dim3(8, 32), 512, 0, stream>>>(
        xb, 1024, Wqb, 1024, nullptr, Qb, nullptr, 1024, 1024, 0, 0.06f);
    gemm8_k<128, 3><<<dim3(8, 32), 512, 0, stream>>>(
        xb, 1024, Wkb, 1024, nullptr, Kb, nullptr, 1024, 1024, 0, 1.0f);
    gemm8_k<128, 3><<<dim3(8, 32), 512, 0, stream>>>(
        xb, 1024, Wvb, 1024, nullptr, Vb, nullptr, 1024, 1024, 0, 1.0f);
    transpose_bf16<<<dim3(16, 128), 256, 0, stream>>>(Vb, Vt, 1024, 8192);

    // 4) logits 2 chunks of 4096 rows: GEMM -> row stats -> fused norm+dual-write
    for (int c = 0; c < 2; ++c) {
        gemm8_k<256, 0><<<dim3(32, 16), 512, 0, stream>>>(
            Qb + (size_t)c * 4096 * 1024, 1024, Kb, 1024,
            Sf, nullptr, nullptr, 8192, 1024, 0, 1.0f);
        stats_k<<<4096, 256, 0, stream>>>(Sf, rowm, rowl);
        nt_k<<<dim3(128, 64), 256, 0, stream>>>(Sf, rowm, rowl,
            aw + (size_t)c * 4096 * 8192, ST, c * 4096);
    }

    // 5) PV split-K z=2 (BN=256): y01 slices; yb = bf16(y0+y1)
    gemm8_k<256, 0><<<dim3(4, 32, 2), 512, 0, stream>>>(
        ST, 8192, Vt, 8192, y01, nullptr, nullptr, 1024, 4096, NM, 1.0f);
    cvt2_k<<<4096, 256, 0, stream>>>(y01, y01 + NM, yb);

    // 6) head: y2 = yb@Wo^T ; zb = LN(y2+mn) ; h = relu(zb@ka^T+b) ; out
    gemm8_k<128, 0><<<dim3(8, 32), 512, 0, stream>>>(
        yb, 1024, Wob, 1024, y2, nullptr, nullptr, 1024, 1024, 0, 1.0f);
    ln_y_k<<<8192, 256, 0, stream>>>(y2, mn, lyg, lyb, zb);
    gemm8_k<128, 1><<<dim3(8, 32), 512, 0, stream>>>(
        zb, 1024, kwb, 1024, hbuf, nullptr, kab, 1024, 1024, 0, 1.0f);
    ln_dot_k<<<8192, 256, 0, stream>>>(hbuf, lkg, lkb, kdw, kdb, out0);
}